// Round 1
// baseline (736.149 us; speedup 1.0000x reference)
//
#include <hip/hip_runtime.h>
#include <math.h>

#define N_NODES 50000
#define N_EDGES 600000
#define IN_DIM 128
#define HID_DIM 512

// ---------------------------------------------------------------------------
// CSR build: degree count -> exclusive scan -> bucket fill
// ---------------------------------------------------------------------------

__global__ void degree_kernel(const int* __restrict__ dst, int* __restrict__ deg) {
    int i = blockIdx.x * blockDim.x + threadIdx.x;
    if (i < N_EDGES) atomicAdd(&deg[dst[i]], 1);
}

__global__ void scan_kernel(const int* __restrict__ deg, int* __restrict__ offsets,
                            int* __restrict__ cursor) {
    __shared__ int sums[1024];
    const int N = N_NODES;
    int t = threadIdx.x;
    int chunk = (N + 1023) >> 10;   // 49
    int lo = t * chunk;
    int hi = min(lo + chunk, N);
    int s = 0;
    for (int i = lo; i < hi; ++i) s += deg[i];
    sums[t] = s;
    __syncthreads();
    for (int off = 1; off < 1024; off <<= 1) {
        int v = 0;
        if (t >= off) v = sums[t - off];
        __syncthreads();
        if (t >= off) sums[t] += v;
        __syncthreads();
    }
    int run = (t == 0) ? 0 : sums[t - 1];
    for (int i = lo; i < hi; ++i) {
        int d = deg[i];
        offsets[i] = run;
        cursor[i] = run;
        run += d;
    }
    if (t == 1023) offsets[N] = sums[1023];
}

__global__ void csr_fill_kernel(const int* __restrict__ src, const int* __restrict__ dst,
                                int* __restrict__ cursor, int* __restrict__ csr_src) {
    int i = blockIdx.x * blockDim.x + threadIdx.x;
    if (i < N_EDGES) {
        int p = atomicAdd(&cursor[dst[i]], 1);
        csr_src[p] = src[i];
    }
}

// ---------------------------------------------------------------------------
// Layer-1 mean aggregation: agg1[n][:] = mean over incoming src of x[src][:]
// One block (128 threads) per node; per edge the block reads 512 contiguous B.
// ---------------------------------------------------------------------------

__global__ __launch_bounds__(IN_DIM) void agg1_kernel(
    const float* __restrict__ x, const int* __restrict__ offsets,
    const int* __restrict__ csr_src, float* __restrict__ agg1) {
    int n = blockIdx.x;
    int t = threadIdx.x;
    int s0 = offsets[n], s1 = offsets[n + 1];
    float acc = 0.f;
    for (int e = s0; e < s1; ++e) {
        int s = csr_src[e];
        acc += x[(size_t)s * IN_DIM + t];
    }
    float inv = 1.0f / fmaxf((float)(s1 - s0), 1.0f);
    agg1[(size_t)n * IN_DIM + t] = acc * inv;
}

// ---------------------------------------------------------------------------
// GEMM1: h = relu(agg1 @ W1l + x @ W1r + b1)
// Treated as one [M x 256] @ [256 x 512] GEMM with concatenated K.
// Register-tiled f32 SGEMM: BM=BN=64, BK=64, TM=TN=4, 256 threads.
// ---------------------------------------------------------------------------

__global__ __launch_bounds__(256) void gemm1_kernel(
    const float* __restrict__ agg1, const float* __restrict__ x,
    const float* __restrict__ W1l, const float* __restrict__ W1r,
    const float* __restrict__ b1, float* __restrict__ h) {
    const int M = N_NODES;
    // [k][m] layout; row stride 68 floats = 272 B keeps 16B alignment for
    // vectorizable reads of 4 consecutive m, and (68%32==4) limits write
    // conflicts to 8-way on the staging store only.
    __shared__ float As[64][68];
    __shared__ float Bs[64][68];
    int tid = threadIdx.x;
    int tr = tid >> 4;   // 0..15
    int tc = tid & 15;   // 0..15
    int row0 = blockIdx.x * 64;
    int col0 = blockIdx.y * 64;
    float acc[4][4] = {};
    for (int k0 = 0; k0 < 2 * IN_DIM; k0 += 64) {
        const bool first = (k0 < IN_DIM);
        const float* Aarr = first ? agg1 : x;
        const float* Warr = first ? W1l : W1r;
        int kbase = first ? k0 : (k0 - IN_DIM);
#pragma unroll
        for (int i = 0; i < 16; ++i) {
            int idx = tid + i * 256;
            int k = idx & 63;        // consecutive lanes -> consecutive k: coalesced
            int m = idx >> 6;
            int gr = row0 + m;
            float v = 0.f;
            if (gr < M) v = Aarr[(size_t)gr * IN_DIM + kbase + k];
            As[k][m] = v;
        }
#pragma unroll
        for (int i = 0; i < 16; ++i) {
            int idx = tid + i * 256;
            int j = idx & 63;        // consecutive lanes -> consecutive j: coalesced
            int k = idx >> 6;
            Bs[k][j] = Warr[(size_t)(kbase + k) * HID_DIM + col0 + j];
        }
        __syncthreads();
#pragma unroll 16
        for (int kk = 0; kk < 64; ++kk) {
            float a[4], b[4];
#pragma unroll
            for (int i = 0; i < 4; ++i) a[i] = As[kk][tr * 4 + i];
#pragma unroll
            for (int j = 0; j < 4; ++j) b[j] = Bs[kk][tc * 4 + j];
#pragma unroll
            for (int i = 0; i < 4; ++i)
#pragma unroll
                for (int j = 0; j < 4; ++j)
                    acc[i][j] += a[i] * b[j];
        }
        __syncthreads();
    }
#pragma unroll
    for (int i = 0; i < 4; ++i) {
        int gr = row0 + tr * 4 + i;
        if (gr >= M) continue;
#pragma unroll
        for (int j = 0; j < 4; ++j) {
            int gc = col0 + tc * 4 + j;
            float v = acc[i][j] + b1[gc];
            h[(size_t)gr * HID_DIM + gc] = fmaxf(v, 0.f);
        }
    }
}

// ---------------------------------------------------------------------------
// Layer 2 fused: agg2 = mean over incoming of h[src]; out = log_softmax(
//   agg2 @ W2l + b2 + h[n] @ W2r ). One block (256 threads) per node.
// agg2 never materialized: each thread holds 2 of the 512 features, then the
// [512 x 2] dot is a block reduction.
// ---------------------------------------------------------------------------

__global__ __launch_bounds__(256) void layer2_kernel(
    const float* __restrict__ h, const int* __restrict__ offsets,
    const int* __restrict__ csr_src, const float* __restrict__ W2l,
    const float* __restrict__ b2, const float* __restrict__ W2r,
    float* __restrict__ out) {
    int n = blockIdx.x;
    int t = threadIdx.x;
    int f0 = t, f1 = t + 256;
    int s0 = offsets[n], s1 = offsets[n + 1];
    float a0 = 0.f, a1 = 0.f;
    for (int e = s0; e < s1; ++e) {
        int s = csr_src[e];
        const float* hr = h + (size_t)s * HID_DIM;
        a0 += hr[f0];
        a1 += hr[f1];
    }
    float inv = 1.0f / fmaxf((float)(s1 - s0), 1.0f);
    a0 *= inv;
    a1 *= inv;
    float h0 = h[(size_t)n * HID_DIM + f0];
    float h1 = h[(size_t)n * HID_DIM + f1];
    float p0 = a0 * W2l[f0 * 2 + 0] + a1 * W2l[f1 * 2 + 0]
             + h0 * W2r[f0 * 2 + 0] + h1 * W2r[f1 * 2 + 0];
    float p1 = a0 * W2l[f0 * 2 + 1] + a1 * W2l[f1 * 2 + 1]
             + h0 * W2r[f0 * 2 + 1] + h1 * W2r[f1 * 2 + 1];
    // block reduction: wave shuffle then cross-wave via LDS
#pragma unroll
    for (int off = 32; off > 0; off >>= 1) {
        p0 += __shfl_down(p0, off);
        p1 += __shfl_down(p1, off);
    }
    __shared__ float r0[4], r1[4];
    int wave = t >> 6, lane = t & 63;
    if (lane == 0) { r0[wave] = p0; r1[wave] = p1; }
    __syncthreads();
    if (t == 0) {
        float o0 = r0[0] + r0[1] + r0[2] + r0[3] + b2[0];
        float o1 = r1[0] + r1[1] + r1[2] + r1[3] + b2[1];
        float m = fmaxf(o0, o1);
        float l = logf(expf(o0 - m) + expf(o1 - m));
        out[(size_t)n * 2 + 0] = (o0 - m) - l;
        out[(size_t)n * 2 + 1] = (o1 - m) - l;
    }
}

// ---------------------------------------------------------------------------

extern "C" void kernel_launch(void* const* d_in, const int* in_sizes, int n_in,
                              void* d_out, int out_size, void* d_ws, size_t ws_size,
                              hipStream_t stream) {
    const float* x   = (const float*)d_in[0];
    const float* W1l = (const float*)d_in[1];
    const float* b1  = (const float*)d_in[2];
    const float* W1r = (const float*)d_in[3];
    const float* W2l = (const float*)d_in[4];
    const float* b2  = (const float*)d_in[5];
    const float* W2r = (const float*)d_in[6];
    const int* edge  = (const int*)d_in[7];
    const int* src = edge;             // edge_index[0]
    const int* dst = edge + N_EDGES;   // edge_index[1]
    float* out = (float*)d_out;

    char* ws = (char*)d_ws;
    size_t off = 0;
    auto alloc = [&](size_t bytes) -> void* {
        void* p = ws + off;
        off += (bytes + 255) & ~(size_t)255;
        return p;
    };
    int* deg      = (int*)alloc((size_t)N_NODES * 4);
    int* offsets  = (int*)alloc((size_t)(N_NODES + 1) * 4);
    int* cursor   = (int*)alloc((size_t)N_NODES * 4);
    int* csr_src  = (int*)alloc((size_t)N_EDGES * 4);
    float* agg1   = (float*)alloc((size_t)N_NODES * IN_DIM * 4);
    float* h      = (float*)alloc((size_t)N_NODES * HID_DIM * 4);

    hipMemsetAsync(deg, 0, (size_t)N_NODES * 4, stream);
    degree_kernel<<<(N_EDGES + 255) / 256, 256, 0, stream>>>(dst, deg);
    scan_kernel<<<1, 1024, 0, stream>>>(deg, offsets, cursor);
    csr_fill_kernel<<<(N_EDGES + 255) / 256, 256, 0, stream>>>(src, dst, cursor, csr_src);
    agg1_kernel<<<N_NODES, IN_DIM, 0, stream>>>(x, offsets, csr_src, agg1);
    gemm1_kernel<<<dim3((N_NODES + 63) / 64, HID_DIM / 64), 256, 0, stream>>>(
        agg1, x, W1l, W1r, b1, h);
    layer2_kernel<<<N_NODES, 256, 0, stream>>>(h, offsets, csr_src, W2l, b2, W2r, out);
}

// Round 2
// 381.604 us; speedup vs baseline: 1.9291x; 1.9291x over previous
//
#include <hip/hip_runtime.h>
#include <math.h>
#include <stdint.h>

#define N_NODES 50000
#define N_EDGES 600000
#define IN_DIM 128
#define HID_DIM 512
#define M_PAD 50048   // 391 * 128

typedef __bf16 bf16;
typedef __bf16 bf16x2 __attribute__((ext_vector_type(2)));
typedef __bf16 bf16x4 __attribute__((ext_vector_type(4)));
typedef __bf16 bf16x8 __attribute__((ext_vector_type(8)));
typedef float f32x4 __attribute__((ext_vector_type(4)));

// ---------------------------------------------------------------------------
// CSR build: degree count -> exclusive scan -> bucket fill
// ---------------------------------------------------------------------------

__global__ void degree_kernel(const int* __restrict__ dst, int* __restrict__ deg) {
    int i = blockIdx.x * blockDim.x + threadIdx.x;
    if (i < N_EDGES) atomicAdd(&deg[dst[i]], 1);
}

__global__ void scan_kernel(const int* __restrict__ deg, int* __restrict__ offsets,
                            int* __restrict__ cursor) {
    __shared__ int sums[1024];
    const int N = N_NODES;
    int t = threadIdx.x;
    int chunk = (N + 1023) >> 10;
    int lo = t * chunk;
    int hi = min(lo + chunk, N);
    int s = 0;
    for (int i = lo; i < hi; ++i) s += deg[i];
    sums[t] = s;
    __syncthreads();
    for (int off = 1; off < 1024; off <<= 1) {
        int v = 0;
        if (t >= off) v = sums[t - off];
        __syncthreads();
        if (t >= off) sums[t] += v;
        __syncthreads();
    }
    int run = (t == 0) ? 0 : sums[t - 1];
    for (int i = lo; i < hi; ++i) {
        int d = deg[i];
        offsets[i] = run;
        cursor[i] = run;
        run += d;
    }
    if (t == 1023) offsets[N] = sums[1023];
}

__global__ void csr_fill_kernel(const int* __restrict__ src, const int* __restrict__ dst,
                                int* __restrict__ cursor, int* __restrict__ csr_src) {
    int i = blockIdx.x * blockDim.x + threadIdx.x;
    if (i < N_EDGES) {
        int p = atomicAdd(&cursor[dst[i]], 1);
        csr_src[p] = src[i];
    }
}

// ---------------------------------------------------------------------------
// Casts: x -> bf16; W1l/W1r -> transposed bf16 Wt[512][256] (Wt[n][k])
// ---------------------------------------------------------------------------

__global__ void cast_x_kernel(const float* __restrict__ x, bf16* __restrict__ xb) {
    int i = blockIdx.x * blockDim.x + threadIdx.x;   // 1.6M threads, 4 elems each
    float4 v = ((const float4*)x)[i];
    bf16x4 o = {(bf16)v.x, (bf16)v.y, (bf16)v.z, (bf16)v.w};
    *(bf16x4*)(xb + (size_t)i * 4) = o;
}

__global__ void cast_w_kernel(const float* __restrict__ W1l, const float* __restrict__ W1r,
                              bf16* __restrict__ Wt) {
    int idx = blockIdx.x * blockDim.x + threadIdx.x;  // 512*256 threads
    int n = idx >> 8;        // 0..511
    int k = idx & 255;       // 0..255
    float v = (k < IN_DIM) ? W1l[(size_t)k * HID_DIM + n]
                           : W1r[(size_t)(k - IN_DIM) * HID_DIM + n];
    Wt[idx] = (bf16)v;
}

// ---------------------------------------------------------------------------
// Layer-1 mean aggregation (bf16 in/out, f32 accumulate).
// One wave per node; lane l covers cols {2l, 2l+1} (4B/lane per edge row).
// ---------------------------------------------------------------------------

__global__ __launch_bounds__(256) void agg1_kernel(
    const bf16* __restrict__ xb, const int* __restrict__ offsets,
    const int* __restrict__ csr_src, bf16* __restrict__ agg1b) {
    int w = threadIdx.x >> 6, l = threadIdx.x & 63;
    int n = blockIdx.x * 4 + w;
    int s0 = offsets[n], s1 = offsets[n + 1];
    float a0 = 0.f, a1 = 0.f;
    for (int e = s0; e < s1; ++e) {
        int s = csr_src[e];
        bf16x2 v = *(const bf16x2*)(xb + (size_t)s * IN_DIM + 2 * l);
        a0 += (float)v[0];
        a1 += (float)v[1];
    }
    float inv = 1.0f / fmaxf((float)(s1 - s0), 1.0f);
    bf16x2 o = {(bf16)(a0 * inv), (bf16)(a1 * inv)};
    *(bf16x2*)(agg1b + (size_t)n * IN_DIM + 2 * l) = o;
}

// ---------------------------------------------------------------------------
// GEMM1 (bf16 MFMA): h = relu([agg1b | xb] @ Wt^T + b1), M=50048, N=512, K=256
// 128x128 tile, BK=32, 4 waves, 16x16x32 MFMA, global_load_lds width-16 staging.
// ---------------------------------------------------------------------------

__global__ __launch_bounds__(256) void gemm1_kernel(
    const bf16* __restrict__ agg1b, const bf16* __restrict__ xb,
    const bf16* __restrict__ Wt, const float* __restrict__ b1,
    float* __restrict__ h) {
    __shared__ bf16 As[128][32];   // [m][k], 64B rows
    __shared__ bf16 Bs[128][32];   // [n][k], 64B rows (B^T)
    int tid = threadIdx.x;
    int w = tid >> 6;
    int lane = tid & 63;
    int q = lane >> 4, rr = lane & 15;
    int row0 = blockIdx.x * 128;
    int n0 = blockIdx.y * 128;
    int wm = (w & 1) * 64, wn = (w >> 1) * 64;
    int lr = lane >> 2;          // staging row within 16-row chunk
    int lc = (lane & 3) * 8;     // staging k-offset (elems)
    f32x4 acc[4][4] = {};
    for (int k0 = 0; k0 < 8; ++k0) {
        const bf16* Asrc;
        int kb;
        if (k0 < 4) { Asrc = agg1b; kb = k0 * 32; }
        else        { Asrc = xb;    kb = k0 * 32 - IN_DIM; }
        int kw = k0 * 32;
#pragma unroll
        for (int j = 0; j < 2; ++j) {
            int r = w * 32 + j * 16 + lr;
            const bf16* ga = Asrc + (size_t)(row0 + r) * IN_DIM + kb + lc;
            __builtin_amdgcn_global_load_lds(
                (const __attribute__((address_space(1))) uint32_t*)ga,
                (__attribute__((address_space(3))) uint32_t*)&As[w * 32 + j * 16][0],
                16, 0, 0);
            const bf16* gb = Wt + (size_t)(n0 + r) * 256 + kw + lc;
            __builtin_amdgcn_global_load_lds(
                (const __attribute__((address_space(1))) uint32_t*)gb,
                (__attribute__((address_space(3))) uint32_t*)&Bs[w * 32 + j * 16][0],
                16, 0, 0);
        }
        __syncthreads();
        bf16x8 af[4], bfr[4];
#pragma unroll
        for (int i = 0; i < 4; ++i) af[i] = *(const bf16x8*)&As[wm + i * 16 + rr][q * 8];
#pragma unroll
        for (int j = 0; j < 4; ++j) bfr[j] = *(const bf16x8*)&Bs[wn + j * 16 + rr][q * 8];
#pragma unroll
        for (int i = 0; i < 4; ++i)
#pragma unroll
            for (int j = 0; j < 4; ++j)
                acc[i][j] = __builtin_amdgcn_mfma_f32_16x16x32_bf16(
                    af[i], bfr[j], acc[i][j], 0, 0, 0);
        __syncthreads();
    }
    // epilogue: C/D layout col=lane&15, row=quad*4+reg [m89-verified]
#pragma unroll
    for (int i = 0; i < 4; ++i) {
#pragma unroll
        for (int rg = 0; rg < 4; ++rg) {
            int gr = row0 + wm + i * 16 + q * 4 + rg;
            if (gr >= N_NODES) continue;
#pragma unroll
            for (int j = 0; j < 4; ++j) {
                int gc = n0 + wn + j * 16 + rr;
                float v = acc[i][j][rg] + b1[gc];
                h[(size_t)gr * HID_DIM + gc] = fmaxf(v, 0.f);
            }
        }
    }
}

// ---------------------------------------------------------------------------
// zr: z[n][0..1] = h[n] @ W2l ; z[n][2..3] = h[n] @ W2r  (transform BEFORE agg)
// One wave per node; lane covers 8 cols; W2 rows held in registers.
// ---------------------------------------------------------------------------

__global__ __launch_bounds__(256) void zr_kernel(
    const float* __restrict__ h, const float* __restrict__ W2l,
    const float* __restrict__ W2r, float* __restrict__ z) {
    int t = threadIdx.x;
    int w = t >> 6, l = t & 63;
    int c0 = l * 8;
    // per-lane weights: rows c0..c0+7 of W2l and W2r (16 floats each)
    float wl[8][2], wr[8][2];
#pragma unroll
    for (int u = 0; u < 8; ++u) {
        float2 a = *(const float2*)(W2l + (size_t)(c0 + u) * 2);
        float2 b = *(const float2*)(W2r + (size_t)(c0 + u) * 2);
        wl[u][0] = a.x; wl[u][1] = a.y;
        wr[u][0] = b.x; wr[u][1] = b.y;
    }
    for (int it = 0; it < 8; ++it) {
        int n = blockIdx.x * 32 + w * 8 + it;
        if (n >= N_NODES) return;
        const float* hr = h + (size_t)n * HID_DIM + c0;
        float4 v0 = *(const float4*)hr;
        float4 v1 = *(const float4*)(hr + 4);
        float hv[8] = {v0.x, v0.y, v0.z, v0.w, v1.x, v1.y, v1.z, v1.w};
        float a0 = 0.f, a1 = 0.f, a2 = 0.f, a3 = 0.f;
#pragma unroll
        for (int u = 0; u < 8; ++u) {
            a0 += hv[u] * wl[u][0];
            a1 += hv[u] * wl[u][1];
            a2 += hv[u] * wr[u][0];
            a3 += hv[u] * wr[u][1];
        }
#pragma unroll
        for (int m = 1; m < 64; m <<= 1) {
            a0 += __shfl_xor(a0, m);
            a1 += __shfl_xor(a1, m);
            a2 += __shfl_xor(a2, m);
            a3 += __shfl_xor(a3, m);
        }
        if (l == 0) {
            float4 o = {a0, a1, a2, a3};
            *(float4*)(z + (size_t)n * 4) = o;
        }
    }
}

// ---------------------------------------------------------------------------
// final: out[n] = log_softmax(mean_e z[src][0..1] + b2 + z[n][2..3])
// ---------------------------------------------------------------------------

__global__ void final_kernel(const float* __restrict__ z, const int* __restrict__ offsets,
                             const int* __restrict__ csr_src, const float* __restrict__ b2,
                             float* __restrict__ out) {
    int n = blockIdx.x * blockDim.x + threadIdx.x;
    if (n >= N_NODES) return;
    int s0 = offsets[n], s1 = offsets[n + 1];
    float a0 = 0.f, a1 = 0.f;
    for (int e = s0; e < s1; ++e) {
        int s = csr_src[e];
        float2 v = *(const float2*)(z + (size_t)s * 4);
        a0 += v.x;
        a1 += v.y;
    }
    float inv = 1.0f / fmaxf((float)(s1 - s0), 1.0f);
    float o0 = a0 * inv + b2[0] + z[(size_t)n * 4 + 2];
    float o1 = a1 * inv + b2[1] + z[(size_t)n * 4 + 3];
    float m = fmaxf(o0, o1);
    float lse = logf(expf(o0 - m) + expf(o1 - m));
    float2 o = {o0 - m - lse, o1 - m - lse};
    *(float2*)(out + (size_t)n * 2) = o;
}

// ---------------------------------------------------------------------------

extern "C" void kernel_launch(void* const* d_in, const int* in_sizes, int n_in,
                              void* d_out, int out_size, void* d_ws, size_t ws_size,
                              hipStream_t stream) {
    const float* x   = (const float*)d_in[0];
    const float* W1l = (const float*)d_in[1];
    const float* b1  = (const float*)d_in[2];
    const float* W1r = (const float*)d_in[3];
    const float* W2l = (const float*)d_in[4];
    const float* b2  = (const float*)d_in[5];
    const float* W2r = (const float*)d_in[6];
    const int* edge  = (const int*)d_in[7];
    const int* src = edge;
    const int* dst = edge + N_EDGES;
    float* out = (float*)d_out;

    char* ws = (char*)d_ws;
    size_t off = 0;
    auto alloc = [&](size_t bytes) -> void* {
        void* p = ws + off;
        off += (bytes + 255) & ~(size_t)255;
        return p;
    };
    int* deg     = (int*)alloc((size_t)N_NODES * 4);
    int* offsets = (int*)alloc((size_t)(N_NODES + 1) * 4);
    int* cursor  = (int*)alloc((size_t)N_NODES * 4);
    int* csr_src = (int*)alloc((size_t)N_EDGES * 4);
    bf16* xb     = (bf16*)alloc((size_t)M_PAD * IN_DIM * 2);
    bf16* agg1b  = (bf16*)alloc((size_t)M_PAD * IN_DIM * 2);
    bf16* Wt     = (bf16*)alloc((size_t)HID_DIM * 256 * 2);
    float* h     = (float*)alloc((size_t)M_PAD * HID_DIM * 4);
    float* z     = (float*)alloc((size_t)N_NODES * 4 * 4);

    hipMemsetAsync(deg, 0, (size_t)N_NODES * 4, stream);
    cast_x_kernel<<<(N_NODES * IN_DIM / 4) / 256, 256, 0, stream>>>(x, xb);
    cast_w_kernel<<<(HID_DIM * 256) / 256, 256, 0, stream>>>(W1l, W1r, Wt);
    degree_kernel<<<(N_EDGES + 255) / 256, 256, 0, stream>>>(dst, deg);
    scan_kernel<<<1, 1024, 0, stream>>>(deg, offsets, cursor);
    csr_fill_kernel<<<(N_EDGES + 255) / 256, 256, 0, stream>>>(src, dst, cursor, csr_src);
    agg1_kernel<<<N_NODES / 4, 256, 0, stream>>>(xb, offsets, csr_src, agg1b);
    gemm1_kernel<<<dim3(M_PAD / 128, HID_DIM / 128), 256, 0, stream>>>(
        agg1b, xb, Wt, b1, h);
    zr_kernel<<<(N_NODES + 31) / 32, 256, 0, stream>>>(h, W2l, W2r, z);
    final_kernel<<<(N_NODES + 255) / 256, 256, 0, stream>>>(z, offsets, csr_src, b2, out);
}

// Round 3
// 339.953 us; speedup vs baseline: 2.1654x; 1.1225x over previous
//
#include <hip/hip_runtime.h>
#include <math.h>
#include <stdint.h>

#define N_NODES 50000
#define N_EDGES 600000
#define IN_DIM 128
#define HID_DIM 512
#define M_PAD 50048          // 391 * 128
#define SCAN_NB 196          // ceil(50000/256)

typedef __bf16 bf16;
typedef __bf16 bf16x2 __attribute__((ext_vector_type(2)));
typedef __bf16 bf16x4 __attribute__((ext_vector_type(4)));
typedef __bf16 bf16x8 __attribute__((ext_vector_type(8)));
typedef float f32x4 __attribute__((ext_vector_type(4)));

// ---------------------------------------------------------------------------
// CSR build: degree count -> hierarchical scan (3 small kernels) -> bucket fill
// ---------------------------------------------------------------------------

__global__ void degree_kernel(const int* __restrict__ dst, int* __restrict__ deg) {
    int i = blockIdx.x * blockDim.x + threadIdx.x;
    if (i < N_EDGES) atomicAdd(&deg[dst[i]], 1);
}

__global__ __launch_bounds__(256) void scan1_kernel(const int* __restrict__ deg,
                                                    int* __restrict__ bsum) {
    int t = threadIdx.x;
    int i = blockIdx.x * 256 + t;
    int v = (i < N_NODES) ? deg[i] : 0;
#pragma unroll
    for (int m = 1; m < 64; m <<= 1) v += __shfl_xor(v, m);
    __shared__ int ws_[4];
    int w = t >> 6, l = t & 63;
    if (l == 0) ws_[w] = v;
    __syncthreads();
    if (t == 0) bsum[blockIdx.x] = ws_[0] + ws_[1] + ws_[2] + ws_[3];
}

__global__ __launch_bounds__(256) void scan2_kernel(const int* __restrict__ bsum,
                                                    int* __restrict__ bscan) {
    int t = threadIdx.x;
    int l = t & 63, w = t >> 6;
    int v = (t < SCAN_NB) ? bsum[t] : 0;
#pragma unroll
    for (int off = 1; off < 64; off <<= 1) {
        int y = __shfl_up(v, off);
        if (l >= off) v += y;
    }
    __shared__ int wsum[4];
    if (l == 63) wsum[w] = v;
    __syncthreads();
    int add = 0;
    for (int u = 0; u < w; ++u) add += wsum[u];
    if (t < SCAN_NB) bscan[t] = v + add;   // inclusive scan of block sums
}

__global__ __launch_bounds__(256) void scan3_kernel(const int* __restrict__ deg,
                                                    const int* __restrict__ bscan,
                                                    int* __restrict__ offsets,
                                                    int* __restrict__ cursor) {
    int t = threadIdx.x;
    int blk = blockIdx.x;
    int i = blk * 256 + t;
    int l = t & 63, w = t >> 6;
    int v = (i < N_NODES) ? deg[i] : 0;
    int inc = v;
#pragma unroll
    for (int off = 1; off < 64; off <<= 1) {
        int y = __shfl_up(inc, off);
        if (l >= off) inc += y;
    }
    __shared__ int wsum[4];
    if (l == 63) wsum[w] = inc;
    __syncthreads();
    int add = (blk > 0) ? bscan[blk - 1] : 0;
    for (int u = 0; u < w; ++u) add += wsum[u];
    int ex = add + inc - v;
    if (i < N_NODES) { offsets[i] = ex; cursor[i] = ex; }
    if (blk == 0 && t == 0) offsets[N_NODES] = N_EDGES;
}

__global__ void csr_fill_kernel(const int* __restrict__ src, const int* __restrict__ dst,
                                int* __restrict__ cursor, int* __restrict__ csr_src) {
    int i = blockIdx.x * blockDim.x + threadIdx.x;
    if (i < N_EDGES) {
        int p = atomicAdd(&cursor[dst[i]], 1);
        csr_src[p] = src[i];
    }
}

// ---------------------------------------------------------------------------
// Casts: x -> bf16; W1l/W1r -> transposed bf16 Wt[512][256] (Wt[n][k])
// ---------------------------------------------------------------------------

__global__ void cast_x_kernel(const float* __restrict__ x, bf16* __restrict__ xb) {
    int i = blockIdx.x * blockDim.x + threadIdx.x;
    float4 v = ((const float4*)x)[i];
    bf16x4 o = {(bf16)v.x, (bf16)v.y, (bf16)v.z, (bf16)v.w};
    *(bf16x4*)(xb + (size_t)i * 4) = o;
}

__global__ void cast_w_kernel(const float* __restrict__ W1l, const float* __restrict__ W1r,
                              bf16* __restrict__ Wt) {
    int idx = blockIdx.x * blockDim.x + threadIdx.x;
    int n = idx >> 8;
    int k = idx & 255;
    float v = (k < IN_DIM) ? W1l[(size_t)k * HID_DIM + n]
                           : W1r[(size_t)(k - IN_DIM) * HID_DIM + n];
    Wt[idx] = (bf16)v;
}

// ---------------------------------------------------------------------------
// Layer-1 mean aggregation (bf16 in/out, f32 accumulate). One wave per node.
// ---------------------------------------------------------------------------

__global__ __launch_bounds__(256) void agg1_kernel(
    const bf16* __restrict__ xb, const int* __restrict__ offsets,
    const int* __restrict__ csr_src, bf16* __restrict__ agg1b) {
    int w = threadIdx.x >> 6, l = threadIdx.x & 63;
    int n = blockIdx.x * 4 + w;
    int s0 = offsets[n], s1 = offsets[n + 1];
    float a0 = 0.f, a1 = 0.f;
    for (int e = s0; e < s1; ++e) {
        int s = csr_src[e];
        bf16x2 v = *(const bf16x2*)(xb + (size_t)s * IN_DIM + 2 * l);
        a0 += (float)v[0];
        a1 += (float)v[1];
    }
    float inv = 1.0f / fmaxf((float)(s1 - s0), 1.0f);
    bf16x2 o = {(bf16)(a0 * inv), (bf16)(a1 * inv)};
    *(bf16x2*)(agg1b + (size_t)n * IN_DIM + 2 * l) = o;
}

// ---------------------------------------------------------------------------
// GEMM1 + fused layer-2 projection. h = relu([agg1b|xb] @ Wt^T + b1) exists
// only in registers; epilogue computes partial z[n][0..3] = h[n] @ [W2l|W2r]
// over this block's 128 cols and atomicAdds into z.  h (102 MB) never hits HBM.
// ---------------------------------------------------------------------------

__global__ __launch_bounds__(256) void gemm1_kernel(
    const bf16* __restrict__ agg1b, const bf16* __restrict__ xb,
    const bf16* __restrict__ Wt, const float* __restrict__ b1,
    const float* __restrict__ W2l, const float* __restrict__ W2r,
    float* __restrict__ z) {
    __shared__ bf16 As[128][32];   // [m][k]
    __shared__ bf16 Bs[128][32];   // [n][k] (B^T)
    int tid = threadIdx.x;
    int w = tid >> 6;
    int lane = tid & 63;
    int q = lane >> 4, rr = lane & 15;
    int row0 = blockIdx.x * 128;
    int n0 = blockIdx.y * 128;
    int wm = (w & 1) * 64, wn = (w >> 1) * 64;
    int lr = lane >> 2;
    int lc = (lane & 3) * 8;
    f32x4 acc[4][4] = {};
    for (int k0 = 0; k0 < 8; ++k0) {
        const bf16* Asrc;
        int kb;
        if (k0 < 4) { Asrc = agg1b; kb = k0 * 32; }
        else        { Asrc = xb;    kb = k0 * 32 - IN_DIM; }
        int kw = k0 * 32;
#pragma unroll
        for (int j = 0; j < 2; ++j) {
            int r = w * 32 + j * 16 + lr;
            const bf16* ga = Asrc + (size_t)(row0 + r) * IN_DIM + kb + lc;
            __builtin_amdgcn_global_load_lds(
                (const __attribute__((address_space(1))) uint32_t*)ga,
                (__attribute__((address_space(3))) uint32_t*)&As[w * 32 + j * 16][0],
                16, 0, 0);
            const bf16* gb = Wt + (size_t)(n0 + r) * 256 + kw + lc;
            __builtin_amdgcn_global_load_lds(
                (const __attribute__((address_space(1))) uint32_t*)gb,
                (__attribute__((address_space(3))) uint32_t*)&Bs[w * 32 + j * 16][0],
                16, 0, 0);
        }
        __syncthreads();
        bf16x8 af[4], bfr[4];
#pragma unroll
        for (int i = 0; i < 4; ++i) af[i] = *(const bf16x8*)&As[wm + i * 16 + rr][q * 8];
#pragma unroll
        for (int j = 0; j < 4; ++j) bfr[j] = *(const bf16x8*)&Bs[wn + j * 16 + rr][q * 8];
#pragma unroll
        for (int i = 0; i < 4; ++i)
#pragma unroll
            for (int j = 0; j < 4; ++j)
                acc[i][j] = __builtin_amdgcn_mfma_f32_16x16x32_bf16(
                    af[i], bfr[j], acc[i][j], 0, 0, 0);
        __syncthreads();
    }
    // epilogue: lane holds cols gc(j) = n0+wn+j*16+rr for rows q*4+rg (+i*16).
    float bias[4];
    float2 wl2[4], wr2[4];
#pragma unroll
    for (int j = 0; j < 4; ++j) {
        int gc = n0 + wn + j * 16 + rr;
        bias[j] = b1[gc];
        wl2[j] = *(const float2*)(W2l + (size_t)gc * 2);
        wr2[j] = *(const float2*)(W2r + (size_t)gc * 2);
    }
#pragma unroll
    for (int i = 0; i < 4; ++i) {
#pragma unroll
        for (int rg = 0; rg < 4; ++rg) {
            int gr = row0 + wm + i * 16 + q * 4 + rg;
            float s0 = 0.f, s1 = 0.f, s2 = 0.f, s3 = 0.f;
#pragma unroll
            for (int j = 0; j < 4; ++j) {
                float hv = fmaxf(acc[i][j][rg] + bias[j], 0.f);
                s0 += hv * wl2[j].x;
                s1 += hv * wl2[j].y;
                s2 += hv * wr2[j].x;
                s3 += hv * wr2[j].y;
            }
            // reduce across the 16 lanes (rr = lane bits 0..3) sharing this row
#pragma unroll
            for (int m = 1; m < 16; m <<= 1) {
                s0 += __shfl_xor(s0, m);
                s1 += __shfl_xor(s1, m);
                s2 += __shfl_xor(s2, m);
                s3 += __shfl_xor(s3, m);
            }
            if (rr == 0 && gr < N_NODES) {
                atomicAdd(&z[(size_t)gr * 4 + 0], s0);
                atomicAdd(&z[(size_t)gr * 4 + 1], s1);
                atomicAdd(&z[(size_t)gr * 4 + 2], s2);
                atomicAdd(&z[(size_t)gr * 4 + 3], s3);
            }
        }
    }
}

// ---------------------------------------------------------------------------
// final: out[n] = log_softmax(mean_e z[src][0..1] + b2 + z[n][2..3])
// ---------------------------------------------------------------------------

__global__ void final_kernel(const float* __restrict__ z, const int* __restrict__ offsets,
                             const int* __restrict__ csr_src, const float* __restrict__ b2,
                             float* __restrict__ out) {
    int n = blockIdx.x * blockDim.x + threadIdx.x;
    if (n >= N_NODES) return;
    int s0 = offsets[n], s1 = offsets[n + 1];
    float a0 = 0.f, a1 = 0.f;
    for (int e = s0; e < s1; ++e) {
        int s = csr_src[e];
        float2 v = *(const float2*)(z + (size_t)s * 4);
        a0 += v.x;
        a1 += v.y;
    }
    float inv = 1.0f / fmaxf((float)(s1 - s0), 1.0f);
    float o0 = a0 * inv + b2[0] + z[(size_t)n * 4 + 2];
    float o1 = a1 * inv + b2[1] + z[(size_t)n * 4 + 3];
    float m = fmaxf(o0, o1);
    float lse = logf(expf(o0 - m) + expf(o1 - m));
    float2 o = {o0 - m - lse, o1 - m - lse};
    *(float2*)(out + (size_t)n * 2) = o;
}

// ---------------------------------------------------------------------------

extern "C" void kernel_launch(void* const* d_in, const int* in_sizes, int n_in,
                              void* d_out, int out_size, void* d_ws, size_t ws_size,
                              hipStream_t stream) {
    const float* x   = (const float*)d_in[0];
    const float* W1l = (const float*)d_in[1];
    const float* b1  = (const float*)d_in[2];
    const float* W1r = (const float*)d_in[3];
    const float* W2l = (const float*)d_in[4];
    const float* b2  = (const float*)d_in[5];
    const float* W2r = (const float*)d_in[6];
    const int* edge  = (const int*)d_in[7];
    const int* src = edge;
    const int* dst = edge + N_EDGES;
    float* out = (float*)d_out;

    char* ws = (char*)d_ws;
    size_t off = 0;
    auto alloc = [&](size_t bytes) -> void* {
        void* p = ws + off;
        off += (bytes + 255) & ~(size_t)255;
        return p;
    };
    int* deg     = (int*)alloc((size_t)N_NODES * 4);
    int* offsets = (int*)alloc((size_t)(N_NODES + 1) * 4);
    int* cursor  = (int*)alloc((size_t)N_NODES * 4);
    int* csr_src = (int*)alloc((size_t)N_EDGES * 4);
    int* bsum    = (int*)alloc((size_t)SCAN_NB * 4);
    int* bscan   = (int*)alloc((size_t)SCAN_NB * 4);
    bf16* xb     = (bf16*)alloc((size_t)M_PAD * IN_DIM * 2);
    bf16* agg1b  = (bf16*)alloc((size_t)M_PAD * IN_DIM * 2);
    bf16* Wt     = (bf16*)alloc((size_t)HID_DIM * 256 * 2);
    float* z     = (float*)alloc((size_t)N_NODES * 4 * 4);

    hipMemsetAsync(deg, 0, (size_t)N_NODES * 4, stream);
    hipMemsetAsync(z, 0, (size_t)N_NODES * 4 * 4, stream);
    cast_x_kernel<<<(N_NODES * IN_DIM / 4) / 256, 256, 0, stream>>>(x, xb);
    cast_w_kernel<<<(HID_DIM * 256) / 256, 256, 0, stream>>>(W1l, W1r, Wt);
    degree_kernel<<<(N_EDGES + 255) / 256, 256, 0, stream>>>(dst, deg);
    scan1_kernel<<<SCAN_NB, 256, 0, stream>>>(deg, bsum);
    scan2_kernel<<<1, 256, 0, stream>>>(bsum, bscan);
    scan3_kernel<<<SCAN_NB, 256, 0, stream>>>(deg, bscan, offsets, cursor);
    csr_fill_kernel<<<(N_EDGES + 255) / 256, 256, 0, stream>>>(src, dst, cursor, csr_src);
    agg1_kernel<<<N_NODES / 4, 256, 0, stream>>>(xb, offsets, csr_src, agg1b);
    gemm1_kernel<<<dim3(M_PAD / 128, HID_DIM / 128), 256, 0, stream>>>(
        agg1b, xb, Wt, b1, W2l, W2r, z);
    final_kernel<<<(N_NODES + 255) / 256, 256, 0, stream>>>(z, offsets, csr_src, b2, out);
}

// Round 4
// 244.158 us; speedup vs baseline: 3.0150x; 1.3923x over previous
//
#include <hip/hip_runtime.h>
#include <math.h>
#include <stdint.h>

#define N_NODES 50000
#define N_EDGES 600000
#define IN_DIM 128
#define HID_DIM 512
#define M_PAD 50048          // 391 * 128
#define SCAN_NB 196          // ceil(50000/256)

typedef __bf16 bf16;
typedef __bf16 bf16x2 __attribute__((ext_vector_type(2)));
typedef __bf16 bf16x4 __attribute__((ext_vector_type(4)));
typedef __bf16 bf16x8 __attribute__((ext_vector_type(8)));
typedef float f32x4 __attribute__((ext_vector_type(4)));

#define GLDS(gp, lp) __builtin_amdgcn_global_load_lds( \
    (const __attribute__((address_space(1))) uint32_t*)(gp), \
    (__attribute__((address_space(3))) uint32_t*)(lp), 16, 0, 0)

// ---------------------------------------------------------------------------
// CSR build: degree count -> hierarchical scan -> bucket fill
// ---------------------------------------------------------------------------

__global__ void degree_kernel(const int* __restrict__ dst, int* __restrict__ deg) {
    int i = blockIdx.x * blockDim.x + threadIdx.x;
    if (i < N_EDGES) atomicAdd(&deg[dst[i]], 1);
}

__global__ __launch_bounds__(256) void scan1_kernel(const int* __restrict__ deg,
                                                    int* __restrict__ bsum) {
    int t = threadIdx.x;
    int i = blockIdx.x * 256 + t;
    int v = (i < N_NODES) ? deg[i] : 0;
#pragma unroll
    for (int m = 1; m < 64; m <<= 1) v += __shfl_xor(v, m);
    __shared__ int ws_[4];
    int w = t >> 6, l = t & 63;
    if (l == 0) ws_[w] = v;
    __syncthreads();
    if (t == 0) bsum[blockIdx.x] = ws_[0] + ws_[1] + ws_[2] + ws_[3];
}

__global__ __launch_bounds__(256) void scan2_kernel(const int* __restrict__ bsum,
                                                    int* __restrict__ bscan) {
    int t = threadIdx.x;
    int l = t & 63, w = t >> 6;
    int v = (t < SCAN_NB) ? bsum[t] : 0;
#pragma unroll
    for (int off = 1; off < 64; off <<= 1) {
        int y = __shfl_up(v, off);
        if (l >= off) v += y;
    }
    __shared__ int wsum[4];
    if (l == 63) wsum[w] = v;
    __syncthreads();
    int add = 0;
    for (int u = 0; u < w; ++u) add += wsum[u];
    if (t < SCAN_NB) bscan[t] = v + add;
}

__global__ __launch_bounds__(256) void scan3_kernel(const int* __restrict__ deg,
                                                    const int* __restrict__ bscan,
                                                    int* __restrict__ offsets,
                                                    int* __restrict__ cursor) {
    int t = threadIdx.x;
    int blk = blockIdx.x;
    int i = blk * 256 + t;
    int l = t & 63, w = t >> 6;
    int v = (i < N_NODES) ? deg[i] : 0;
    int inc = v;
#pragma unroll
    for (int off = 1; off < 64; off <<= 1) {
        int y = __shfl_up(inc, off);
        if (l >= off) inc += y;
    }
    __shared__ int wsum[4];
    if (l == 63) wsum[w] = inc;
    __syncthreads();
    int add = (blk > 0) ? bscan[blk - 1] : 0;
    for (int u = 0; u < w; ++u) add += wsum[u];
    int ex = add + inc - v;
    if (i < N_NODES) { offsets[i] = ex; cursor[i] = ex; }
    if (blk == 0 && t == 0) offsets[N_NODES] = N_EDGES;
}

__global__ void csr_fill_kernel(const int* __restrict__ src, const int* __restrict__ dst,
                                int* __restrict__ cursor, int* __restrict__ csr_src) {
    int i = blockIdx.x * blockDim.x + threadIdx.x;
    if (i < N_EDGES) {
        int p = atomicAdd(&cursor[dst[i]], 1);
        csr_src[p] = src[i];
    }
}

// ---------------------------------------------------------------------------
// Casts
// ---------------------------------------------------------------------------

__global__ void cast_x_kernel(const float* __restrict__ x, bf16* __restrict__ xb) {
    int i = blockIdx.x * blockDim.x + threadIdx.x;
    float4 v = ((const float4*)x)[i];
    bf16x4 o = {(bf16)v.x, (bf16)v.y, (bf16)v.z, (bf16)v.w};
    *(bf16x4*)(xb + (size_t)i * 4) = o;
}

__global__ void cast_w_kernel(const float* __restrict__ W1l, const float* __restrict__ W1r,
                              bf16* __restrict__ Wt) {
    int idx = blockIdx.x * blockDim.x + threadIdx.x;
    int n = idx >> 8;
    int k = idx & 255;
    float v = (k < IN_DIM) ? W1l[(size_t)k * HID_DIM + n]
                           : W1r[(size_t)(k - IN_DIM) * HID_DIM + n];
    Wt[idx] = (bf16)v;
}

// ---------------------------------------------------------------------------
// Layer-1 mean aggregation, 4-way edge unroll for memory-level parallelism.
// ---------------------------------------------------------------------------

__global__ __launch_bounds__(256) void agg1_kernel(
    const bf16* __restrict__ xb, const int* __restrict__ offsets,
    const int* __restrict__ csr_src, bf16* __restrict__ agg1b) {
    int w = threadIdx.x >> 6, l = threadIdx.x & 63;
    int n = blockIdx.x * 4 + w;
    int s0 = offsets[n], s1 = offsets[n + 1];
    float a0 = 0.f, a1 = 0.f;
    int e = s0;
    for (; e + 4 <= s1; e += 4) {
        int i0 = csr_src[e], i1 = csr_src[e + 1];
        int i2 = csr_src[e + 2], i3 = csr_src[e + 3];
        bf16x2 v0 = *(const bf16x2*)(xb + (size_t)i0 * IN_DIM + 2 * l);
        bf16x2 v1 = *(const bf16x2*)(xb + (size_t)i1 * IN_DIM + 2 * l);
        bf16x2 v2 = *(const bf16x2*)(xb + (size_t)i2 * IN_DIM + 2 * l);
        bf16x2 v3 = *(const bf16x2*)(xb + (size_t)i3 * IN_DIM + 2 * l);
        a0 += (float)v0[0] + (float)v1[0] + (float)v2[0] + (float)v3[0];
        a1 += (float)v0[1] + (float)v1[1] + (float)v2[1] + (float)v3[1];
    }
    for (; e < s1; ++e) {
        int s = csr_src[e];
        bf16x2 v = *(const bf16x2*)(xb + (size_t)s * IN_DIM + 2 * l);
        a0 += (float)v[0];
        a1 += (float)v[1];
    }
    float inv = 1.0f / fmaxf((float)(s1 - s0), 1.0f);
    bf16x2 o = {(bf16)(a0 * inv), (bf16)(a1 * inv)};
    *(bf16x2*)(agg1b + (size_t)n * IN_DIM + 2 * l) = o;
}

// ---------------------------------------------------------------------------
// GEMM1 (bf16 MFMA): h = relu([agg1b|xb] @ Wt^T + b1) -> bf16 h.
// BK=64 via split half-buffers (8 barrier-drains instead of 16).
// grid = (4 col-blocks, 391 row-blocks): col-blocks sharing A are
// dispatch-adjacent -> co-resident -> A fetched from HBM once.
// ---------------------------------------------------------------------------

__global__ __launch_bounds__(256) void gemm1_kernel(
    const bf16* __restrict__ agg1b, const bf16* __restrict__ xb,
    const bf16* __restrict__ Wt, const float* __restrict__ b1,
    bf16* __restrict__ h) {
    __shared__ bf16 As[2][128][32];   // [k-half][m][k32]
    __shared__ bf16 Bs[2][128][32];   // [k-half][n][k32]
    int tid = threadIdx.x;
    int w = tid >> 6;
    int lane = tid & 63;
    int q = lane >> 4, rr = lane & 15;
    int n0 = blockIdx.x * 128;     // 0..3
    int row0 = blockIdx.y * 128;   // 0..390
    int wm = (w & 1) * 64, wn = (w >> 1) * 64;
    int lr = lane >> 2;            // staging row 0..15
    int lc = (lane & 3) * 8;       // staging k-offset (elems)
    f32x4 acc[4][4] = {};
#pragma unroll
    for (int k0 = 0; k0 < 4; ++k0) {        // K chunks of 64
        const bf16* Asrc;
        int kb;
        if (k0 < 2) { Asrc = agg1b; kb = k0 * 64; }
        else        { Asrc = xb;    kb = k0 * 64 - IN_DIM; }
        int kw = k0 * 64;
#pragma unroll
        for (int half = 0; half < 2; ++half) {
#pragma unroll
            for (int j = 0; j < 2; ++j) {
                int r = w * 32 + j * 16 + lr;
                GLDS(Asrc + (size_t)(row0 + r) * IN_DIM + kb + half * 32 + lc,
                     &As[half][w * 32 + j * 16][0]);
                GLDS(Wt + (size_t)(n0 + r) * 256 + kw + half * 32 + lc,
                     &Bs[half][w * 32 + j * 16][0]);
            }
        }
        __syncthreads();
#pragma unroll
        for (int half = 0; half < 2; ++half) {
            bf16x8 af[4], bfr[4];
#pragma unroll
            for (int i = 0; i < 4; ++i)
                af[i] = *(const bf16x8*)&As[half][wm + i * 16 + rr][q * 8];
#pragma unroll
            for (int j = 0; j < 4; ++j)
                bfr[j] = *(const bf16x8*)&Bs[half][wn + j * 16 + rr][q * 8];
#pragma unroll
            for (int i = 0; i < 4; ++i)
#pragma unroll
                for (int j = 0; j < 4; ++j)
                    acc[i][j] = __builtin_amdgcn_mfma_f32_16x16x32_bf16(
                        af[i], bfr[j], acc[i][j], 0, 0, 0);
        }
        __syncthreads();
    }
    float bias[4];
#pragma unroll
    for (int j = 0; j < 4; ++j) bias[j] = b1[n0 + wn + j * 16 + rr];
#pragma unroll
    for (int i = 0; i < 4; ++i) {
#pragma unroll
        for (int rg = 0; rg < 4; ++rg) {
            int gr = row0 + wm + i * 16 + q * 4 + rg;
#pragma unroll
            for (int j = 0; j < 4; ++j) {
                int gc = n0 + wn + j * 16 + rr;
                float v = fmaxf(acc[i][j][rg] + bias[j], 0.f);
                h[(size_t)gr * HID_DIM + gc] = (bf16)v;
            }
        }
    }
}

// ---------------------------------------------------------------------------
// zr: z[n][0..1] = h[n] @ W2l ; z[n][2..3] = h[n] @ W2r   (transform-first)
// One wave per node, coalesced 1KB row read, 64-lane shuffle reduce.
// ---------------------------------------------------------------------------

__global__ __launch_bounds__(256) void zr_kernel(
    const bf16* __restrict__ h, const float* __restrict__ W2l,
    const float* __restrict__ W2r, float* __restrict__ z) {
    int t = threadIdx.x;
    int w = t >> 6, l = t & 63;
    int n = blockIdx.x * 4 + w;
    int c0 = l * 8;
    float wl[8][2], wr[8][2];
#pragma unroll
    for (int u = 0; u < 8; ++u) {
        float2 a = *(const float2*)(W2l + (size_t)(c0 + u) * 2);
        float2 b = *(const float2*)(W2r + (size_t)(c0 + u) * 2);
        wl[u][0] = a.x; wl[u][1] = a.y;
        wr[u][0] = b.x; wr[u][1] = b.y;
    }
    bf16x8 hv = *(const bf16x8*)(h + (size_t)n * HID_DIM + c0);
    float s0 = 0.f, s1 = 0.f, s2 = 0.f, s3 = 0.f;
#pragma unroll
    for (int u = 0; u < 8; ++u) {
        float v = (float)hv[u];
        s0 += v * wl[u][0];
        s1 += v * wl[u][1];
        s2 += v * wr[u][0];
        s3 += v * wr[u][1];
    }
#pragma unroll
    for (int m = 1; m < 64; m <<= 1) {
        s0 += __shfl_xor(s0, m);
        s1 += __shfl_xor(s1, m);
        s2 += __shfl_xor(s2, m);
        s3 += __shfl_xor(s3, m);
    }
    if (l == 0) {
        float4 o = {s0, s1, s2, s3};
        *(float4*)(z + (size_t)n * 4) = o;
    }
}

// ---------------------------------------------------------------------------
// final: out[n] = log_softmax(mean_e z[src][0..1] + b2 + z[n][2..3])
// ---------------------------------------------------------------------------

__global__ void final_kernel(const float* __restrict__ z, const int* __restrict__ offsets,
                             const int* __restrict__ csr_src, const float* __restrict__ b2,
                             float* __restrict__ out) {
    int n = blockIdx.x * blockDim.x + threadIdx.x;
    if (n >= N_NODES) return;
    int s0 = offsets[n], s1 = offsets[n + 1];
    float a0 = 0.f, a1 = 0.f;
    int e = s0;
    for (; e + 4 <= s1; e += 4) {
        int i0 = csr_src[e], i1 = csr_src[e + 1];
        int i2 = csr_src[e + 2], i3 = csr_src[e + 3];
        float2 v0 = *(const float2*)(z + (size_t)i0 * 4);
        float2 v1 = *(const float2*)(z + (size_t)i1 * 4);
        float2 v2 = *(const float2*)(z + (size_t)i2 * 4);
        float2 v3 = *(const float2*)(z + (size_t)i3 * 4);
        a0 += v0.x + v1.x + v2.x + v3.x;
        a1 += v0.y + v1.y + v2.y + v3.y;
    }
    for (; e < s1; ++e) {
        int s = csr_src[e];
        float2 v = *(const float2*)(z + (size_t)s * 4);
        a0 += v.x;
        a1 += v.y;
    }
    float inv = 1.0f / fmaxf((float)(s1 - s0), 1.0f);
    float o0 = a0 * inv + b2[0] + z[(size_t)n * 4 + 2];
    float o1 = a1 * inv + b2[1] + z[(size_t)n * 4 + 3];
    float m = fmaxf(o0, o1);
    float lse = logf(expf(o0 - m) + expf(o1 - m));
    float2 o = {o0 - m - lse, o1 - m - lse};
    *(float2*)(out + (size_t)n * 2) = o;
}

// ---------------------------------------------------------------------------

extern "C" void kernel_launch(void* const* d_in, const int* in_sizes, int n_in,
                              void* d_out, int out_size, void* d_ws, size_t ws_size,
                              hipStream_t stream) {
    const float* x   = (const float*)d_in[0];
    const float* W1l = (const float*)d_in[1];
    const float* b1  = (const float*)d_in[2];
    const float* W1r = (const float*)d_in[3];
    const float* W2l = (const float*)d_in[4];
    const float* b2  = (const float*)d_in[5];
    const float* W2r = (const float*)d_in[6];
    const int* edge  = (const int*)d_in[7];
    const int* src = edge;
    const int* dst = edge + N_EDGES;
    float* out = (float*)d_out;

    char* ws = (char*)d_ws;
    size_t off = 0;
    auto alloc = [&](size_t bytes) -> void* {
        void* p = ws + off;
        off += (bytes + 255) & ~(size_t)255;
        return p;
    };
    int* deg     = (int*)alloc((size_t)N_NODES * 4);
    int* offsets = (int*)alloc((size_t)(N_NODES + 1) * 4);
    int* cursor  = (int*)alloc((size_t)N_NODES * 4);
    int* csr_src = (int*)alloc((size_t)N_EDGES * 4);
    int* bsum    = (int*)alloc((size_t)SCAN_NB * 4);
    int* bscan   = (int*)alloc((size_t)SCAN_NB * 4);
    bf16* xb     = (bf16*)alloc((size_t)M_PAD * IN_DIM * 2);
    bf16* agg1b  = (bf16*)alloc((size_t)M_PAD * IN_DIM * 2);
    bf16* Wt     = (bf16*)alloc((size_t)HID_DIM * 256 * 2);
    bf16* h      = (bf16*)alloc((size_t)M_PAD * HID_DIM * 2);
    float* z     = (float*)alloc((size_t)N_NODES * 4 * 4);

    hipMemsetAsync(deg, 0, (size_t)N_NODES * 4, stream);
    cast_x_kernel<<<(N_NODES * IN_DIM / 4) / 256, 256, 0, stream>>>(x, xb);
    cast_w_kernel<<<(HID_DIM * 256) / 256, 256, 0, stream>>>(W1l, W1r, Wt);
    degree_kernel<<<(N_EDGES + 255) / 256, 256, 0, stream>>>(dst, deg);
    scan1_kernel<<<SCAN_NB, 256, 0, stream>>>(deg, bsum);
    scan2_kernel<<<1, 256, 0, stream>>>(bsum, bscan);
    scan3_kernel<<<SCAN_NB, 256, 0, stream>>>(deg, bscan, offsets, cursor);
    csr_fill_kernel<<<(N_EDGES + 255) / 256, 256, 0, stream>>>(src, dst, cursor, csr_src);
    agg1_kernel<<<N_NODES / 4, 256, 0, stream>>>(xb, offsets, csr_src, agg1b);
    gemm1_kernel<<<dim3(4, M_PAD / 128), 256, 0, stream>>>(agg1b, xb, Wt, b1, h);
    zr_kernel<<<N_NODES / 4, 256, 0, stream>>>(h, W2l, W2r, z);
    final_kernel<<<(N_NODES + 255) / 256, 256, 0, stream>>>(z, offsets, csr_src, b2, out);
}

// Round 5
// 217.801 us; speedup vs baseline: 3.3799x; 1.1210x over previous
//
#include <hip/hip_runtime.h>
#include <math.h>
#include <stdint.h>

#define N_NODES 50000
#define N_EDGES 600000
#define IN_DIM 128
#define HID_DIM 512
#define M_PAD 50048          // 391 * 128
#define SCAN_NB 196          // ceil(50000/256)

typedef __bf16 bf16;
typedef __bf16 bf16x2 __attribute__((ext_vector_type(2)));
typedef __bf16 bf16x4 __attribute__((ext_vector_type(4)));
typedef __bf16 bf16x8 __attribute__((ext_vector_type(8)));
typedef float f32x4 __attribute__((ext_vector_type(4)));

#define GLDS(gp, lp) __builtin_amdgcn_global_load_lds( \
    (const __attribute__((address_space(1))) uint32_t*)(gp), \
    (__attribute__((address_space(3))) uint32_t*)(lp), 16, 0, 0)

// ---------------------------------------------------------------------------
// CSR build: degree count -> hierarchical scan -> bucket fill
// ---------------------------------------------------------------------------

__global__ void degree_kernel(const int* __restrict__ dst, int* __restrict__ deg) {
    int i = blockIdx.x * blockDim.x + threadIdx.x;
    if (i < N_EDGES) atomicAdd(&deg[dst[i]], 1);
}

__global__ __launch_bounds__(256) void scan1_kernel(const int* __restrict__ deg,
                                                    int* __restrict__ bsum) {
    int t = threadIdx.x;
    int i = blockIdx.x * 256 + t;
    int v = (i < N_NODES) ? deg[i] : 0;
#pragma unroll
    for (int m = 1; m < 64; m <<= 1) v += __shfl_xor(v, m);
    __shared__ int ws_[4];
    int w = t >> 6, l = t & 63;
    if (l == 0) ws_[w] = v;
    __syncthreads();
    if (t == 0) bsum[blockIdx.x] = ws_[0] + ws_[1] + ws_[2] + ws_[3];
}

__global__ __launch_bounds__(256) void scan2_kernel(const int* __restrict__ bsum,
                                                    int* __restrict__ bscan) {
    int t = threadIdx.x;
    int l = t & 63, w = t >> 6;
    int v = (t < SCAN_NB) ? bsum[t] : 0;
#pragma unroll
    for (int off = 1; off < 64; off <<= 1) {
        int y = __shfl_up(v, off);
        if (l >= off) v += y;
    }
    __shared__ int wsum[4];
    if (l == 63) wsum[w] = v;
    __syncthreads();
    int add = 0;
    for (int u = 0; u < w; ++u) add += wsum[u];
    if (t < SCAN_NB) bscan[t] = v + add;
}

__global__ __launch_bounds__(256) void scan3_kernel(const int* __restrict__ deg,
                                                    const int* __restrict__ bscan,
                                                    int* __restrict__ offsets,
                                                    int* __restrict__ cursor) {
    int t = threadIdx.x;
    int blk = blockIdx.x;
    int i = blk * 256 + t;
    int l = t & 63, w = t >> 6;
    int v = (i < N_NODES) ? deg[i] : 0;
    int inc = v;
#pragma unroll
    for (int off = 1; off < 64; off <<= 1) {
        int y = __shfl_up(inc, off);
        if (l >= off) inc += y;
    }
    __shared__ int wsum[4];
    if (l == 63) wsum[w] = inc;
    __syncthreads();
    int add = (blk > 0) ? bscan[blk - 1] : 0;
    for (int u = 0; u < w; ++u) add += wsum[u];
    int ex = add + inc - v;
    if (i < N_NODES) { offsets[i] = ex; cursor[i] = ex; }
    if (blk == 0 && t == 0) offsets[N_NODES] = N_EDGES;
}

__global__ void csr_fill_kernel(const int* __restrict__ src, const int* __restrict__ dst,
                                int* __restrict__ cursor, int* __restrict__ csr_src) {
    int i = blockIdx.x * blockDim.x + threadIdx.x;
    if (i < N_EDGES) {
        int p = atomicAdd(&cursor[dst[i]], 1);
        csr_src[p] = src[i];
    }
}

// ---------------------------------------------------------------------------
// Casts
// ---------------------------------------------------------------------------

__global__ void cast_x_kernel(const float* __restrict__ x, bf16* __restrict__ xb) {
    int i = blockIdx.x * blockDim.x + threadIdx.x;
    float4 v = ((const float4*)x)[i];
    bf16x4 o = {(bf16)v.x, (bf16)v.y, (bf16)v.z, (bf16)v.w};
    *(bf16x4*)(xb + (size_t)i * 4) = o;
}

// Wt[512][256] (layer-1 weights, transposed) and W2bt[16][512]
// (B-operand for the z-projection MFMA: rows 0,1 = W2l cols; 2,3 = W2r cols;
// 4..15 zero).
__global__ void cast_w_kernel(const float* __restrict__ W1l, const float* __restrict__ W1r,
                              const float* __restrict__ W2l, const float* __restrict__ W2r,
                              bf16* __restrict__ Wt, bf16* __restrict__ W2bt) {
    int idx = blockIdx.x * blockDim.x + threadIdx.x;
    if (idx < 512 * 256) {
        int n = idx >> 8;
        int k = idx & 255;
        float v = (k < IN_DIM) ? W1l[(size_t)k * HID_DIM + n]
                               : W1r[(size_t)(k - IN_DIM) * HID_DIM + n];
        Wt[idx] = (bf16)v;
    } else {
        int j = idx - 512 * 256;       // < 16*512
        int n = j >> 9;                // 0..15
        int k = j & 511;
        float v = 0.f;
        if (n == 0) v = W2l[k * 2 + 0];
        else if (n == 1) v = W2l[k * 2 + 1];
        else if (n == 2) v = W2r[k * 2 + 0];
        else if (n == 3) v = W2r[k * 2 + 1];
        W2bt[j] = (bf16)v;
    }
}

// ---------------------------------------------------------------------------
// Layer-1 mean aggregation, 4-way edge unroll for memory-level parallelism.
// ---------------------------------------------------------------------------

__global__ __launch_bounds__(256) void agg1_kernel(
    const bf16* __restrict__ xb, const int* __restrict__ offsets,
    const int* __restrict__ csr_src, bf16* __restrict__ agg1b) {
    int w = threadIdx.x >> 6, l = threadIdx.x & 63;
    int n = blockIdx.x * 4 + w;
    int s0 = offsets[n], s1 = offsets[n + 1];
    float a0 = 0.f, a1 = 0.f;
    int e = s0;
    for (; e + 4 <= s1; e += 4) {
        int i0 = csr_src[e], i1 = csr_src[e + 1];
        int i2 = csr_src[e + 2], i3 = csr_src[e + 3];
        bf16x2 v0 = *(const bf16x2*)(xb + (size_t)i0 * IN_DIM + 2 * l);
        bf16x2 v1 = *(const bf16x2*)(xb + (size_t)i1 * IN_DIM + 2 * l);
        bf16x2 v2 = *(const bf16x2*)(xb + (size_t)i2 * IN_DIM + 2 * l);
        bf16x2 v3 = *(const bf16x2*)(xb + (size_t)i3 * IN_DIM + 2 * l);
        a0 += (float)v0[0] + (float)v1[0] + (float)v2[0] + (float)v3[0];
        a1 += (float)v0[1] + (float)v1[1] + (float)v2[1] + (float)v3[1];
    }
    for (; e < s1; ++e) {
        int s = csr_src[e];
        bf16x2 v = *(const bf16x2*)(xb + (size_t)s * IN_DIM + 2 * l);
        a0 += (float)v[0];
        a1 += (float)v[1];
    }
    float inv = 1.0f / fmaxf((float)(s1 - s0), 1.0f);
    bf16x2 o = {(bf16)(a0 * inv), (bf16)(a1 * inv)};
    *(bf16x2*)(agg1b + (size_t)n * IN_DIM + 2 * l) = o;
}

// ---------------------------------------------------------------------------
// GEMM1 + MFMA z-epilogue.  h = relu([agg1b|xb] @ Wt^T + b1) lives only in
// LDS; epilogue computes zpart[node][cb*4+0..3] = h_tile @ [W2l|W2r] over this
// block's 128 cols via a second MFMA pass.  No h in HBM, no atomics.
// grid = (4 col-blocks, 391 row-blocks) so col-blocks sharing A are
// dispatch-adjacent -> A served from L2 once.
// ---------------------------------------------------------------------------

__global__ __launch_bounds__(256) void gemm1_kernel(
    const bf16* __restrict__ agg1b, const bf16* __restrict__ xb,
    const bf16* __restrict__ Wt, const float* __restrict__ b1,
    const bf16* __restrict__ W2bt, float* __restrict__ zpart) {
    // As[2][128][32] @ 0 (16KB), Bs[2][128][32] @ 16KB; Hs[128][136] aliases
    // the whole 34.8KB after the main loop.
    __shared__ __align__(16) char smem[128 * 136 * 2];
    bf16 (*As)[128][32] = (bf16(*)[128][32])smem;
    bf16 (*Bs)[128][32] = (bf16(*)[128][32])(smem + 16384);
    bf16 (*Hs)[136] = (bf16(*)[136])smem;
    int tid = threadIdx.x;
    int w = tid >> 6;
    int lane = tid & 63;
    int q = lane >> 4, rr = lane & 15;
    int cb = blockIdx.x;           // 0..3
    int n0 = cb * 128;
    int row0 = blockIdx.y * 128;   // 0..390
    int wm = (w & 1) * 64, wn = (w >> 1) * 64;
    f32x4 acc[4][4] = {};
#pragma unroll
    for (int k0 = 0; k0 < 4; ++k0) {        // K chunks of 64
        const bf16* Asrc;
        int kb;
        if (k0 < 2) { Asrc = agg1b; kb = k0 * 64; }
        else        { Asrc = xb;    kb = k0 * 64 - IN_DIM; }
        int kw = k0 * 64;
        int lr = lane >> 2;
        int lc = (lane & 3) * 8;
#pragma unroll
        for (int half = 0; half < 2; ++half) {
#pragma unroll
            for (int j = 0; j < 2; ++j) {
                int r = w * 32 + j * 16 + lr;
                GLDS(Asrc + (size_t)(row0 + r) * IN_DIM + kb + half * 32 + lc,
                     &As[half][w * 32 + j * 16][0]);
                GLDS(Wt + (size_t)(n0 + r) * 256 + kw + half * 32 + lc,
                     &Bs[half][w * 32 + j * 16][0]);
            }
        }
        __syncthreads();
#pragma unroll
        for (int half = 0; half < 2; ++half) {
            bf16x8 af[4], bfr[4];
#pragma unroll
            for (int i = 0; i < 4; ++i)
                af[i] = *(const bf16x8*)&As[half][wm + i * 16 + rr][q * 8];
#pragma unroll
            for (int j = 0; j < 4; ++j)
                bfr[j] = *(const bf16x8*)&Bs[half][wn + j * 16 + rr][q * 8];
#pragma unroll
            for (int i = 0; i < 4; ++i)
#pragma unroll
                for (int j = 0; j < 4; ++j)
                    acc[i][j] = __builtin_amdgcn_mfma_f32_16x16x32_bf16(
                        af[i], bfr[j], acc[i][j], 0, 0, 0);
        }
        __syncthreads();
    }
    // ---- stage h tile (relu'd, bf16) into LDS (aliases As/Bs)
    float bias[4];
#pragma unroll
    for (int j = 0; j < 4; ++j) bias[j] = b1[n0 + wn + j * 16 + rr];
#pragma unroll
    for (int i = 0; i < 4; ++i) {
#pragma unroll
        for (int rg = 0; rg < 4; ++rg) {
            int mrow = wm + i * 16 + q * 4 + rg;
#pragma unroll
            for (int j = 0; j < 4; ++j)
                Hs[mrow][wn + j * 16 + rr] =
                    (bf16)fmaxf(acc[i][j][rg] + bias[j], 0.f);
        }
    }
    __syncthreads();
    // ---- z projection: [128 rows x K=128] @ W2bt^T (16 cols, 4 used)
    bf16x8 wf[4];
#pragma unroll
    for (int ks = 0; ks < 4; ++ks)
        wf[ks] = *(const bf16x8*)(W2bt + (size_t)rr * 512 + n0 + ks * 32 + q * 8);
    f32x4 zacc[2] = {};
#pragma unroll
    for (int mt = 0; mt < 2; ++mt)
#pragma unroll
        for (int ks = 0; ks < 4; ++ks) {
            bf16x8 afz = *(const bf16x8*)&Hs[w * 32 + mt * 16 + rr][ks * 32 + q * 8];
            zacc[mt] = __builtin_amdgcn_mfma_f32_16x16x32_bf16(
                afz, wf[ks], zacc[mt], 0, 0, 0);
        }
    if (rr < 4) {
#pragma unroll
        for (int mt = 0; mt < 2; ++mt)
#pragma unroll
            for (int rg = 0; rg < 4; ++rg) {
                int grow = row0 + w * 32 + mt * 16 + q * 4 + rg;
                zpart[(size_t)grow * 16 + cb * 4 + rr] = zacc[mt][rg];
            }
    }
}

// ---------------------------------------------------------------------------
// zsum: z[n][0..3] = sum of the 4 col-block partials.
// ---------------------------------------------------------------------------

__global__ __launch_bounds__(256) void zsum_kernel(const float* __restrict__ zpart,
                                                   float* __restrict__ z) {
    int n = blockIdx.x * blockDim.x + threadIdx.x;
    if (n >= N_NODES) return;
    const float4* p = (const float4*)(zpart + (size_t)n * 16);
    float4 a = p[0], b = p[1], c = p[2], d = p[3];
    float4 o = {a.x + b.x + c.x + d.x, a.y + b.y + c.y + d.y,
                a.z + b.z + c.z + d.z, a.w + b.w + c.w + d.w};
    *(float4*)(z + (size_t)n * 4) = o;
}

// ---------------------------------------------------------------------------
// final: out[n] = log_softmax(mean_e z[src][0..1] + b2 + z[n][2..3])
// ---------------------------------------------------------------------------

__global__ void final_kernel(const float* __restrict__ z, const int* __restrict__ offsets,
                             const int* __restrict__ csr_src, const float* __restrict__ b2,
                             float* __restrict__ out) {
    int n = blockIdx.x * blockDim.x + threadIdx.x;
    if (n >= N_NODES) return;
    int s0 = offsets[n], s1 = offsets[n + 1];
    float a0 = 0.f, a1 = 0.f;
    int e = s0;
    for (; e + 4 <= s1; e += 4) {
        int i0 = csr_src[e], i1 = csr_src[e + 1];
        int i2 = csr_src[e + 2], i3 = csr_src[e + 3];
        float2 v0 = *(const float2*)(z + (size_t)i0 * 4);
        float2 v1 = *(const float2*)(z + (size_t)i1 * 4);
        float2 v2 = *(const float2*)(z + (size_t)i2 * 4);
        float2 v3 = *(const float2*)(z + (size_t)i3 * 4);
        a0 += v0.x + v1.x + v2.x + v3.x;
        a1 += v0.y + v1.y + v2.y + v3.y;
    }
    for (; e < s1; ++e) {
        int s = csr_src[e];
        float2 v = *(const float2*)(z + (size_t)s * 4);
        a0 += v.x;
        a1 += v.y;
    }
    float inv = 1.0f / fmaxf((float)(s1 - s0), 1.0f);
    float o0 = a0 * inv + b2[0] + z[(size_t)n * 4 + 2];
    float o1 = a1 * inv + b2[1] + z[(size_t)n * 4 + 3];
    float m = fmaxf(o0, o1);
    float lse = logf(expf(o0 - m) + expf(o1 - m));
    float2 o = {o0 - m - lse, o1 - m - lse};
    *(float2*)(out + (size_t)n * 2) = o;
}

// ---------------------------------------------------------------------------

extern "C" void kernel_launch(void* const* d_in, const int* in_sizes, int n_in,
                              void* d_out, int out_size, void* d_ws, size_t ws_size,
                              hipStream_t stream) {
    const float* x   = (const float*)d_in[0];
    const float* W1l = (const float*)d_in[1];
    const float* b1  = (const float*)d_in[2];
    const float* W1r = (const float*)d_in[3];
    const float* W2l = (const float*)d_in[4];
    const float* b2  = (const float*)d_in[5];
    const float* W2r = (const float*)d_in[6];
    const int* edge  = (const int*)d_in[7];
    const int* src = edge;
    const int* dst = edge + N_EDGES;
    float* out = (float*)d_out;

    char* ws = (char*)d_ws;
    size_t off = 0;
    auto alloc = [&](size_t bytes) -> void* {
        void* p = ws + off;
        off += (bytes + 255) & ~(size_t)255;
        return p;
    };
    int* deg     = (int*)alloc((size_t)N_NODES * 4);
    int* offsets = (int*)alloc((size_t)(N_NODES + 1) * 4);
    int* cursor  = (int*)alloc((size_t)N_NODES * 4);
    int* csr_src = (int*)alloc((size_t)N_EDGES * 4);
    int* bsum    = (int*)alloc((size_t)SCAN_NB * 4);
    int* bscan   = (int*)alloc((size_t)SCAN_NB * 4);
    bf16* xb     = (bf16*)alloc((size_t)M_PAD * IN_DIM * 2);
    bf16* agg1b  = (bf16*)alloc((size_t)M_PAD * IN_DIM * 2);
    bf16* Wt     = (bf16*)alloc((size_t)HID_DIM * 256 * 2);
    bf16* W2bt   = (bf16*)alloc((size_t)16 * HID_DIM * 2);
    float* zpart = (float*)alloc((size_t)M_PAD * 16 * 4);
    float* z     = (float*)alloc((size_t)N_NODES * 4 * 4);

    hipMemsetAsync(deg, 0, (size_t)N_NODES * 4, stream);
    cast_x_kernel<<<(N_NODES * IN_DIM / 4) / 256, 256, 0, stream>>>(x, xb);
    cast_w_kernel<<<(512 * 256 + 16 * 512) / 256, 256, 0, stream>>>(
        W1l, W1r, W2l, W2r, Wt, W2bt);
    degree_kernel<<<(N_EDGES + 255) / 256, 256, 0, stream>>>(dst, deg);
    scan1_kernel<<<SCAN_NB, 256, 0, stream>>>(deg, bsum);
    scan2_kernel<<<1, 256, 0, stream>>>(bsum, bscan);
    scan3_kernel<<<SCAN_NB, 256, 0, stream>>>(deg, bscan, offsets, cursor);
    csr_fill_kernel<<<(N_EDGES + 255) / 256, 256, 0, stream>>>(src, dst, cursor, csr_src);
    agg1_kernel<<<N_NODES / 4, 256, 0, stream>>>(xb, offsets, csr_src, agg1b);
    gemm1_kernel<<<dim3(4, M_PAD / 128), 256, 0, stream>>>(
        agg1b, xb, Wt, b1, W2bt, zpart);
    zsum_kernel<<<(N_NODES + 255) / 256, 256, 0, stream>>>(zpart, z);
    final_kernel<<<(N_NODES + 255) / 256, 256, 0, stream>>>(z, offsets, csr_src, b2, out);
}

// Round 6
// 211.053 us; speedup vs baseline: 3.4880x; 1.0320x over previous
//
#include <hip/hip_runtime.h>
#include <math.h>
#include <stdint.h>

#define N_NODES 50000
#define N_EDGES 600000
#define IN_DIM 128
#define HID_DIM 512
#define M_PAD 50048          // 391 * 128
#define SCAN_NB 196          // ceil(50000/256)

// prep_kernel grid partition
#define CASTX_NB 6250        // (50000*128/4)/256
#define DEG_NB   2344        // ceil(600000/256)
#define CASTW_NB 544         // (512*256 + 16*512)/256

typedef __bf16 bf16;
typedef __bf16 bf16x2 __attribute__((ext_vector_type(2)));
typedef __bf16 bf16x4 __attribute__((ext_vector_type(4)));
typedef __bf16 bf16x8 __attribute__((ext_vector_type(8)));
typedef float f32x4 __attribute__((ext_vector_type(4)));

#define GLDS(gp, lp) __builtin_amdgcn_global_load_lds( \
    (const __attribute__((address_space(1))) uint32_t*)(gp), \
    (__attribute__((address_space(3))) uint32_t*)(lp), 16, 0, 0)

// ---------------------------------------------------------------------------
// prep: cast_x + degree-count + cast_w fused (independent work, one launch).
// ---------------------------------------------------------------------------

__global__ __launch_bounds__(256) void prep_kernel(
    const float* __restrict__ x, bf16* __restrict__ xb,
    const int* __restrict__ dst, int* __restrict__ deg,
    const float* __restrict__ W1l, const float* __restrict__ W1r,
    const float* __restrict__ W2l, const float* __restrict__ W2r,
    bf16* __restrict__ Wt, bf16* __restrict__ W2bt) {
    int b = blockIdx.x;
    int t = threadIdx.x;
    if (b < CASTX_NB) {
        int i = b * 256 + t;
        float4 v = ((const float4*)x)[i];
        bf16x4 o = {(bf16)v.x, (bf16)v.y, (bf16)v.z, (bf16)v.w};
        *(bf16x4*)(xb + (size_t)i * 4) = o;
    } else if (b < CASTX_NB + DEG_NB) {
        int i = (b - CASTX_NB) * 256 + t;
        if (i < N_EDGES) atomicAdd(&deg[dst[i]], 1);
    } else {
        int idx = (b - CASTX_NB - DEG_NB) * 256 + t;
        if (idx < 512 * 256) {
            int n = idx >> 8;
            int k = idx & 255;
            float v = (k < IN_DIM) ? W1l[(size_t)k * HID_DIM + n]
                                   : W1r[(size_t)(k - IN_DIM) * HID_DIM + n];
            Wt[idx] = (bf16)v;
        } else {
            int j = idx - 512 * 256;       // < 16*512
            int n = j >> 9;                // 0..15
            int k = j & 511;
            float v = 0.f;
            if (n == 0) v = W2l[k * 2 + 0];
            else if (n == 1) v = W2l[k * 2 + 1];
            else if (n == 2) v = W2r[k * 2 + 0];
            else if (n == 3) v = W2r[k * 2 + 1];
            W2bt[j] = (bf16)v;
        }
    }
}

// ---------------------------------------------------------------------------
// Hierarchical scan -> offsets/cursor; then bucket fill.
// ---------------------------------------------------------------------------

__global__ __launch_bounds__(256) void scan1_kernel(const int* __restrict__ deg,
                                                    int* __restrict__ bsum) {
    int t = threadIdx.x;
    int i = blockIdx.x * 256 + t;
    int v = (i < N_NODES) ? deg[i] : 0;
#pragma unroll
    for (int m = 1; m < 64; m <<= 1) v += __shfl_xor(v, m);
    __shared__ int ws_[4];
    int w = t >> 6, l = t & 63;
    if (l == 0) ws_[w] = v;
    __syncthreads();
    if (t == 0) bsum[blockIdx.x] = ws_[0] + ws_[1] + ws_[2] + ws_[3];
}

__global__ __launch_bounds__(256) void scan2_kernel(const int* __restrict__ bsum,
                                                    int* __restrict__ bscan) {
    int t = threadIdx.x;
    int l = t & 63, w = t >> 6;
    int v = (t < SCAN_NB) ? bsum[t] : 0;
#pragma unroll
    for (int off = 1; off < 64; off <<= 1) {
        int y = __shfl_up(v, off);
        if (l >= off) v += y;
    }
    __shared__ int wsum[4];
    if (l == 63) wsum[w] = v;
    __syncthreads();
    int add = 0;
    for (int u = 0; u < w; ++u) add += wsum[u];
    if (t < SCAN_NB) bscan[t] = v + add;
}

__global__ __launch_bounds__(256) void scan3_kernel(const int* __restrict__ deg,
                                                    const int* __restrict__ bscan,
                                                    int* __restrict__ offsets,
                                                    int* __restrict__ cursor) {
    int t = threadIdx.x;
    int blk = blockIdx.x;
    int i = blk * 256 + t;
    int l = t & 63, w = t >> 6;
    int v = (i < N_NODES) ? deg[i] : 0;
    int inc = v;
#pragma unroll
    for (int off = 1; off < 64; off <<= 1) {
        int y = __shfl_up(inc, off);
        if (l >= off) inc += y;
    }
    __shared__ int wsum[4];
    if (l == 63) wsum[w] = inc;
    __syncthreads();
    int add = (blk > 0) ? bscan[blk - 1] : 0;
    for (int u = 0; u < w; ++u) add += wsum[u];
    int ex = add + inc - v;
    if (i < N_NODES) { offsets[i] = ex; cursor[i] = ex; }
    if (blk == 0 && t == 0) offsets[N_NODES] = N_EDGES;
}

__global__ void csr_fill_kernel(const int* __restrict__ src, const int* __restrict__ dst,
                                int* __restrict__ cursor, int* __restrict__ csr_src) {
    int i = blockIdx.x * blockDim.x + threadIdx.x;
    if (i < N_EDGES) {
        int p = atomicAdd(&cursor[dst[i]], 1);
        csr_src[p] = src[i];
    }
}

// ---------------------------------------------------------------------------
// Layer-1 mean aggregation. One wave per node; half-waves each take one edge
// of a pair (8B bf16x4 per lane, 32 lanes per row), 4-deep unroll = 8 edges
// in flight; halves combined with one shfl_xor(32) at the end.
// ---------------------------------------------------------------------------

__global__ __launch_bounds__(256) void agg1_kernel(
    const bf16* __restrict__ xb, const int* __restrict__ offsets,
    const int* __restrict__ csr_src, bf16* __restrict__ agg1b) {
    int w = threadIdx.x >> 6, l = threadIdx.x & 63;
    int n = blockIdx.x * 4 + w;
    int half = l >> 5;         // 0/1: which edge of the pair
    int sl = l & 31;           // col group: cols sl*4..sl*4+3
    int s0 = offsets[n], s1 = offsets[n + 1];
    float a0 = 0.f, a1 = 0.f, a2 = 0.f, a3 = 0.f;
    int e = s0;
    for (; e + 8 <= s1; e += 8) {
        int i0 = csr_src[e + 0 + half];
        int i1 = csr_src[e + 2 + half];
        int i2 = csr_src[e + 4 + half];
        int i3 = csr_src[e + 6 + half];
        bf16x4 v0 = *(const bf16x4*)(xb + (size_t)i0 * IN_DIM + sl * 4);
        bf16x4 v1 = *(const bf16x4*)(xb + (size_t)i1 * IN_DIM + sl * 4);
        bf16x4 v2 = *(const bf16x4*)(xb + (size_t)i2 * IN_DIM + sl * 4);
        bf16x4 v3 = *(const bf16x4*)(xb + (size_t)i3 * IN_DIM + sl * 4);
        a0 += (float)v0[0] + (float)v1[0] + (float)v2[0] + (float)v3[0];
        a1 += (float)v0[1] + (float)v1[1] + (float)v2[1] + (float)v3[1];
        a2 += (float)v0[2] + (float)v1[2] + (float)v2[2] + (float)v3[2];
        a3 += (float)v0[3] + (float)v1[3] + (float)v2[3] + (float)v3[3];
    }
    for (; e + 2 <= s1; e += 2) {
        int i0 = csr_src[e + half];
        bf16x4 v0 = *(const bf16x4*)(xb + (size_t)i0 * IN_DIM + sl * 4);
        a0 += (float)v0[0];
        a1 += (float)v0[1];
        a2 += (float)v0[2];
        a3 += (float)v0[3];
    }
    if (e < s1 && half == 0) {      // odd tail edge, half 0 only
        int i0 = csr_src[e];
        bf16x4 v0 = *(const bf16x4*)(xb + (size_t)i0 * IN_DIM + sl * 4);
        a0 += (float)v0[0];
        a1 += (float)v0[1];
        a2 += (float)v0[2];
        a3 += (float)v0[3];
    }
    a0 += __shfl_xor(a0, 32);
    a1 += __shfl_xor(a1, 32);
    a2 += __shfl_xor(a2, 32);
    a3 += __shfl_xor(a3, 32);
    if (half == 0) {
        float inv = 1.0f / fmaxf((float)(s1 - s0), 1.0f);
        bf16x4 o = {(bf16)(a0 * inv), (bf16)(a1 * inv),
                    (bf16)(a2 * inv), (bf16)(a3 * inv)};
        *(bf16x4*)(agg1b + (size_t)n * IN_DIM + sl * 4) = o;
    }
}

// ---------------------------------------------------------------------------
// GEMM1 + MFMA z-epilogue, software-pipelined.
// BK=32 x 8 chunks, double-buffered LDS; prefetch of chunk ki+1 is issued
// right after the barrier so its latency overlaps the 16 MFMAs of chunk ki
// (the barrier's vmcnt drain then finds the loads already done).
// h = relu([agg1b|xb] @ Wt^T + b1) lives only in LDS; z-projection via a
// second MFMA pass against W2bt. No h in HBM, no atomics.
// ---------------------------------------------------------------------------

__global__ __launch_bounds__(256) void gemm1_kernel(
    const bf16* __restrict__ agg1b, const bf16* __restrict__ xb,
    const bf16* __restrict__ Wt, const float* __restrict__ b1,
    const bf16* __restrict__ W2bt, float* __restrict__ zpart) {
    // As[2]/Bs[2]: 8KB each buffer half (32KB total); Hs[128][136] aliases
    // the full 34.8KB after the main loop.
    __shared__ __align__(16) char smem[128 * 136 * 2];
    bf16 (*As)[128][32] = (bf16(*)[128][32])smem;
    bf16 (*Bs)[128][32] = (bf16(*)[128][32])(smem + 16384);
    bf16 (*Hs)[136] = (bf16(*)[136])smem;
    int tid = threadIdx.x;
    int w = tid >> 6;
    int lane = tid & 63;
    int q = lane >> 4, rr = lane & 15;
    int cb = blockIdx.x;           // 0..3
    int n0 = cb * 128;
    int row0 = blockIdx.y * 128;   // 0..390
    int wm = (w & 1) * 64, wn = (w >> 1) * 64;
    int lr = lane >> 2;            // staging row 0..15
    int lc = (lane & 3) * 8;       // staging k-offset (elems)

    auto stage = [&](int ki) {
        const bf16* Asrc;
        int kb;
        if (ki < 4) { Asrc = agg1b; kb = ki * 32; }
        else        { Asrc = xb;    kb = ki * 32 - IN_DIM; }
        int kw = ki * 32;
        int buf = ki & 1;
#pragma unroll
        for (int j = 0; j < 2; ++j) {
            int r = w * 32 + j * 16 + lr;
            GLDS(Asrc + (size_t)(row0 + r) * IN_DIM + kb + lc,
                 &As[buf][w * 32 + j * 16][0]);
            GLDS(Wt + (size_t)(n0 + r) * 256 + kw + lc,
                 &Bs[buf][w * 32 + j * 16][0]);
        }
    };

    f32x4 acc[4][4] = {};
    stage(0);
#pragma unroll
    for (int ki = 0; ki < 8; ++ki) {
        __syncthreads();                 // drains stage(ki); guards buf reuse
        if (ki + 1 < 8) stage(ki + 1);   // prefetch overlaps compute below
        int buf = ki & 1;
        bf16x8 af[4], bfr[4];
#pragma unroll
        for (int i = 0; i < 4; ++i)
            af[i] = *(const bf16x8*)&As[buf][wm + i * 16 + rr][q * 8];
#pragma unroll
        for (int j = 0; j < 4; ++j)
            bfr[j] = *(const bf16x8*)&Bs[buf][wn + j * 16 + rr][q * 8];
#pragma unroll
        for (int i = 0; i < 4; ++i)
#pragma unroll
            for (int j = 0; j < 4; ++j)
                acc[i][j] = __builtin_amdgcn_mfma_f32_16x16x32_bf16(
                    af[i], bfr[j], acc[i][j], 0, 0, 0);
    }
    __syncthreads();   // all compute done before Hs aliases As/Bs
    // ---- stage h tile (relu'd, bf16) into LDS
    float bias[4];
#pragma unroll
    for (int j = 0; j < 4; ++j) bias[j] = b1[n0 + wn + j * 16 + rr];
#pragma unroll
    for (int i = 0; i < 4; ++i) {
#pragma unroll
        for (int rg = 0; rg < 4; ++rg) {
            int mrow = wm + i * 16 + q * 4 + rg;
#pragma unroll
            for (int j = 0; j < 4; ++j)
                Hs[mrow][wn + j * 16 + rr] =
                    (bf16)fmaxf(acc[i][j][rg] + bias[j], 0.f);
        }
    }
    __syncthreads();
    // ---- z projection: [128 rows x K=128] @ W2bt^T (16 cols, 4 used)
    bf16x8 wf[4];
#pragma unroll
    for (int ks = 0; ks < 4; ++ks)
        wf[ks] = *(const bf16x8*)(W2bt + (size_t)rr * 512 + n0 + ks * 32 + q * 8);
    f32x4 zacc[2] = {};
#pragma unroll
    for (int mt = 0; mt < 2; ++mt)
#pragma unroll
        for (int ks = 0; ks < 4; ++ks) {
            bf16x8 afz = *(const bf16x8*)&Hs[w * 32 + mt * 16 + rr][ks * 32 + q * 8];
            zacc[mt] = __builtin_amdgcn_mfma_f32_16x16x32_bf16(
                afz, wf[ks], zacc[mt], 0, 0, 0);
        }
    if (rr < 4) {
#pragma unroll
        for (int mt = 0; mt < 2; ++mt)
#pragma unroll
            for (int rg = 0; rg < 4; ++rg) {
                int grow = row0 + w * 32 + mt * 16 + q * 4 + rg;
                zpart[(size_t)grow * 16 + cb * 4 + rr] = zacc[mt][rg];
            }
    }
}

// ---------------------------------------------------------------------------
// zsum: z[n][0..3] = sum of the 4 col-block partials.
// ---------------------------------------------------------------------------

__global__ __launch_bounds__(256) void zsum_kernel(const float* __restrict__ zpart,
                                                   float* __restrict__ z) {
    int n = blockIdx.x * blockDim.x + threadIdx.x;
    if (n >= N_NODES) return;
    const float4* p = (const float4*)(zpart + (size_t)n * 16);
    float4 a = p[0], b = p[1], c = p[2], d = p[3];
    float4 o = {a.x + b.x + c.x + d.x, a.y + b.y + c.y + d.y,
                a.z + b.z + c.z + d.z, a.w + b.w + c.w + d.w};
    *(float4*)(z + (size_t)n * 4) = o;
}

// ---------------------------------------------------------------------------
// final: out[n] = log_softmax(mean_e z[src][0..1] + b2 + z[n][2..3])
// ---------------------------------------------------------------------------

__global__ void final_kernel(const float* __restrict__ z, const int* __restrict__ offsets,
                             const int* __restrict__ csr_src, const float* __restrict__ b2,
                             float* __restrict__ out) {
    int n = blockIdx.x * blockDim.x + threadIdx.x;
    if (n >= N_NODES) return;
    int s0 = offsets[n], s1 = offsets[n + 1];
    float a0 = 0.f, a1 = 0.f;
    int e = s0;
    for (; e + 4 <= s1; e += 4) {
        int i0 = csr_src[e], i1 = csr_src[e + 1];
        int i2 = csr_src[e + 2], i3 = csr_src[e + 3];
        float2 v0 = *(const float2*)(z + (size_t)i0 * 4);
        float2 v1 = *(const float2*)(z + (size_t)i1 * 4);
        float2 v2 = *(const float2*)(z + (size_t)i2 * 4);
        float2 v3 = *(const float2*)(z + (size_t)i3 * 4);
        a0 += v0.x + v1.x + v2.x + v3.x;
        a1 += v0.y + v1.y + v2.y + v3.y;
    }
    for (; e < s1; ++e) {
        int s = csr_src[e];
        float2 v = *(const float2*)(z + (size_t)s * 4);
        a0 += v.x;
        a1 += v.y;
    }
    float inv = 1.0f / fmaxf((float)(s1 - s0), 1.0f);
    float2 zs = *(const float2*)(z + (size_t)n * 4 + 2);
    float o0 = a0 * inv + b2[0] + zs.x;
    float o1 = a1 * inv + b2[1] + zs.y;
    float m = fmaxf(o0, o1);
    float lse = logf(expf(o0 - m) + expf(o1 - m));
    float2 o = {o0 - m - lse, o1 - m - lse};
    *(float2*)(out + (size_t)n * 2) = o;
}

// ---------------------------------------------------------------------------

extern "C" void kernel_launch(void* const* d_in, const int* in_sizes, int n_in,
                              void* d_out, int out_size, void* d_ws, size_t ws_size,
                              hipStream_t stream) {
    const float* x   = (const float*)d_in[0];
    const float* W1l = (const float*)d_in[1];
    const float* b1  = (const float*)d_in[2];
    const float* W1r = (const float*)d_in[3];
    const float* W2l = (const float*)d_in[4];
    const float* b2  = (const float*)d_in[5];
    const float* W2r = (const float*)d_in[6];
    const int* edge  = (const int*)d_in[7];
    const int* src = edge;
    const int* dst = edge + N_EDGES;
    float* out = (float*)d_out;

    char* ws = (char*)d_ws;
    size_t off = 0;
    auto alloc = [&](size_t bytes) -> void* {
        void* p = ws + off;
        off += (bytes + 255) & ~(size_t)255;
        return p;
    };
    int* deg     = (int*)alloc((size_t)N_NODES * 4);
    int* offsets = (int*)alloc((size_t)(N_NODES + 1) * 4);
    int* cursor  = (int*)alloc((size_t)N_NODES * 4);
    int* csr_src = (int*)alloc((size_t)N_EDGES * 4);
    int* bsum    = (int*)alloc((size_t)SCAN_NB * 4);
    int* bscan   = (int*)alloc((size_t)SCAN_NB * 4);
    bf16* xb     = (bf16*)alloc((size_t)M_PAD * IN_DIM * 2);
    bf16* agg1b  = (bf16*)alloc((size_t)M_PAD * IN_DIM * 2);
    bf16* Wt     = (bf16*)alloc((size_t)HID_DIM * 256 * 2);
    bf16* W2bt   = (bf16*)alloc((size_t)16 * HID_DIM * 2);
    float* zpart = (float*)alloc((size_t)M_PAD * 16 * 4);
    float* z     = (float*)alloc((size_t)N_NODES * 4 * 4);

    hipMemsetAsync(deg, 0, (size_t)N_NODES * 4, stream);
    prep_kernel<<<CASTX_NB + DEG_NB + CASTW_NB, 256, 0, stream>>>(
        x, xb, dst, deg, W1l, W1r, W2l, W2r, Wt, W2bt);
    scan1_kernel<<<SCAN_NB, 256, 0, stream>>>(deg, bsum);
    scan2_kernel<<<1, 256, 0, stream>>>(bsum, bscan);
    scan3_kernel<<<SCAN_NB, 256, 0, stream>>>(deg, bscan, offsets, cursor);
    csr_fill_kernel<<<(N_EDGES + 255) / 256, 256, 0, stream>>>(src, dst, cursor, csr_src);
    agg1_kernel<<<N_NODES / 4, 256, 0, stream>>>(xb, offsets, csr_src, agg1b);
    gemm1_kernel<<<dim3(4, M_PAD / 128), 256, 0, stream>>>(
        agg1b, xb, Wt, b1, W2bt, zpart);
    zsum_kernel<<<(N_NODES + 255) / 256, 256, 0, stream>>>(zpart, z);
    final_kernel<<<(N_NODES + 255) / 256, 256, 0, stream>>>(z, offsets, csr_src, b2, out);
}

// Round 7
// 206.573 us; speedup vs baseline: 3.5636x; 1.0217x over previous
//
#include <hip/hip_runtime.h>
#include <math.h>
#include <stdint.h>

#define N_NODES 50000
#define N_EDGES 600000
#define IN_DIM 128
#define HID_DIM 512
#define M_PAD 50048          // 391 * 128
#define SCAN_NB 196          // ceil(50000/256)

// prep_kernel grid partition
#define CASTX_NB 6250        // (50000*128/4)/256
#define DEG_NB   2344        // ceil(600000/256)
#define CASTW_NB 544         // (512*256 + 16*512)/256

typedef __bf16 bf16;
typedef __bf16 bf16x2 __attribute__((ext_vector_type(2)));
typedef __bf16 bf16x4 __attribute__((ext_vector_type(4)));
typedef __bf16 bf16x8 __attribute__((ext_vector_type(8)));
typedef float f32x4 __attribute__((ext_vector_type(4)));

#define GLDS(gp, lp) __builtin_amdgcn_global_load_lds( \
    (const __attribute__((address_space(1))) uint32_t*)(gp), \
    (__attribute__((address_space(3))) uint32_t*)(lp), 16, 0, 0)

// ---------------------------------------------------------------------------
// prep: cast_x + degree-count + cast_w fused (independent work, one launch).
// ---------------------------------------------------------------------------

__global__ __launch_bounds__(256) void prep_kernel(
    const float* __restrict__ x, bf16* __restrict__ xb,
    const int* __restrict__ dst, int* __restrict__ deg,
    const float* __restrict__ W1l, const float* __restrict__ W1r,
    const float* __restrict__ W2l, const float* __restrict__ W2r,
    bf16* __restrict__ Wt, bf16* __restrict__ W2bt) {
    int b = blockIdx.x;
    int t = threadIdx.x;
    if (b < CASTX_NB) {
        int i = b * 256 + t;
        float4 v = ((const float4*)x)[i];
        bf16x4 o = {(bf16)v.x, (bf16)v.y, (bf16)v.z, (bf16)v.w};
        *(bf16x4*)(xb + (size_t)i * 4) = o;
    } else if (b < CASTX_NB + DEG_NB) {
        int i = (b - CASTX_NB) * 256 + t;
        if (i < N_EDGES) atomicAdd(&deg[dst[i]], 1);
    } else {
        int idx = (b - CASTX_NB - DEG_NB) * 256 + t;
        if (idx < 512 * 256) {
            int n = idx >> 8;
            int k = idx & 255;
            float v = (k < IN_DIM) ? W1l[(size_t)k * HID_DIM + n]
                                   : W1r[(size_t)(k - IN_DIM) * HID_DIM + n];
            Wt[idx] = (bf16)v;
        } else {
            int j = idx - 512 * 256;       // < 16*512
            int n = j >> 9;                // 0..15
            int k = j & 511;
            float v = 0.f;
            if (n == 0) v = W2l[k * 2 + 0];
            else if (n == 1) v = W2l[k * 2 + 1];
            else if (n == 2) v = W2r[k * 2 + 0];
            else if (n == 3) v = W2r[k * 2 + 1];
            W2bt[j] = (bf16)v;
        }
    }
}

// ---------------------------------------------------------------------------
// Scan: per-block sums (scan1), then scan3 does its own lookback (masked
// reduction over the 196 block sums with wave 0) — scan2 eliminated.
// ---------------------------------------------------------------------------

__global__ __launch_bounds__(256) void scan1_kernel(const int* __restrict__ deg,
                                                    int* __restrict__ bsum) {
    int t = threadIdx.x;
    int i = blockIdx.x * 256 + t;
    int v = (i < N_NODES) ? deg[i] : 0;
#pragma unroll
    for (int m = 1; m < 64; m <<= 1) v += __shfl_xor(v, m);
    __shared__ int ws_[4];
    int w = t >> 6, l = t & 63;
    if (l == 0) ws_[w] = v;
    __syncthreads();
    if (t == 0) bsum[blockIdx.x] = ws_[0] + ws_[1] + ws_[2] + ws_[3];
}

__global__ __launch_bounds__(256) void scan3_kernel(const int* __restrict__ deg,
                                                    const int* __restrict__ bsum,
                                                    int* __restrict__ offsets,
                                                    int* __restrict__ cursor) {
    int t = threadIdx.x;
    int blk = blockIdx.x;
    int i = blk * 256 + t;
    int l = t & 63, w = t >> 6;
    int v = (i < N_NODES) ? deg[i] : 0;
    int inc = v;
#pragma unroll
    for (int off = 1; off < 64; off <<= 1) {
        int y = __shfl_up(inc, off);
        if (l >= off) inc += y;
    }
    __shared__ int wsum[4];
    __shared__ int lookback;
    if (l == 63) wsum[w] = inc;
    __syncthreads();
    if (t < 64) {           // wave 0: sum of bsum[0..blk-1]
        int s = 0;
        for (int u = t; u < blk; u += 64) s += bsum[u];
#pragma unroll
        for (int m = 1; m < 64; m <<= 1) s += __shfl_xor(s, m);
        if (t == 0) lookback = s;
    }
    __syncthreads();
    int add = lookback;
    for (int u = 0; u < w; ++u) add += wsum[u];
    int ex = add + inc - v;
    if (i < N_NODES) { offsets[i] = ex; cursor[i] = ex; }
    if (blk == 0 && t == 0) offsets[N_NODES] = N_EDGES;
}

__global__ void csr_fill_kernel(const int* __restrict__ src, const int* __restrict__ dst,
                                int* __restrict__ cursor, int* __restrict__ csr_src) {
    int i = blockIdx.x * blockDim.x + threadIdx.x;
    if (i < N_EDGES) {
        int p = atomicAdd(&cursor[dst[i]], 1);
        csr_src[p] = src[i];
    }
}

// ---------------------------------------------------------------------------
// Layer-1 mean aggregation. 16 lanes per node (16B bf16x8 per lane covers the
// 256B row), 4 nodes per wave -> 4 independent edge streams; 4-deep unroll
// gives 16 outstanding gathers per wave. No cross-lane combine needed.
// ---------------------------------------------------------------------------

__global__ __launch_bounds__(256) void agg1_kernel(
    const bf16* __restrict__ xb, const int* __restrict__ offsets,
    const int* __restrict__ csr_src, bf16* __restrict__ agg1b) {
    int t = threadIdx.x;
    int w = t >> 6, l = t & 63;
    int g = l >> 4;            // node subgroup 0..3
    int sl = l & 15;           // 16B chunk index within the 256B row
    int n = blockIdx.x * 16 + w * 4 + g;
    int s0 = offsets[n], s1 = offsets[n + 1];
    float a[8] = {};
    int e = s0;
    for (; e + 4 <= s1; e += 4) {
        int i0 = csr_src[e + 0];
        int i1 = csr_src[e + 1];
        int i2 = csr_src[e + 2];
        int i3 = csr_src[e + 3];
        bf16x8 v0 = *(const bf16x8*)(xb + (size_t)i0 * IN_DIM + sl * 8);
        bf16x8 v1 = *(const bf16x8*)(xb + (size_t)i1 * IN_DIM + sl * 8);
        bf16x8 v2 = *(const bf16x8*)(xb + (size_t)i2 * IN_DIM + sl * 8);
        bf16x8 v3 = *(const bf16x8*)(xb + (size_t)i3 * IN_DIM + sl * 8);
#pragma unroll
        for (int u = 0; u < 8; ++u)
            a[u] += (float)v0[u] + (float)v1[u] + (float)v2[u] + (float)v3[u];
    }
    for (; e < s1; ++e) {
        int i0 = csr_src[e];
        bf16x8 v0 = *(const bf16x8*)(xb + (size_t)i0 * IN_DIM + sl * 8);
#pragma unroll
        for (int u = 0; u < 8; ++u) a[u] += (float)v0[u];
    }
    float inv = 1.0f / fmaxf((float)(s1 - s0), 1.0f);
    bf16x8 o;
#pragma unroll
    for (int u = 0; u < 8; ++u) o[u] = (bf16)(a[u] * inv);
    *(bf16x8*)(agg1b + (size_t)n * IN_DIM + sl * 8) = o;
}

// ---------------------------------------------------------------------------
// GEMM1 + MFMA z-epilogue, software-pipelined (BK=32 x 8, double-buffered).
// h = relu([agg1b|xb] @ Wt^T + b1) lives only in LDS; z-projection via a
// second MFMA pass against W2bt. No h in HBM, no atomics.
// grid (4, 391): col-blocks sharing A are dispatch-adjacent -> A from L2 once.
// ---------------------------------------------------------------------------

__global__ __launch_bounds__(256) void gemm1_kernel(
    const bf16* __restrict__ agg1b, const bf16* __restrict__ xb,
    const bf16* __restrict__ Wt, const float* __restrict__ b1,
    const bf16* __restrict__ W2bt, float* __restrict__ zpart) {
    __shared__ __align__(16) char smem[128 * 136 * 2];
    bf16 (*As)[128][32] = (bf16(*)[128][32])smem;
    bf16 (*Bs)[128][32] = (bf16(*)[128][32])(smem + 16384);
    bf16 (*Hs)[136] = (bf16(*)[136])smem;
    int tid = threadIdx.x;
    int w = tid >> 6;
    int lane = tid & 63;
    int q = lane >> 4, rr = lane & 15;
    int cb = blockIdx.x;           // 0..3
    int n0 = cb * 128;
    int row0 = blockIdx.y * 128;   // 0..390
    int wm = (w & 1) * 64, wn = (w >> 1) * 64;
    int lr = lane >> 2;            // staging row 0..15
    int lc = (lane & 3) * 8;       // staging k-offset (elems)

    auto stage = [&](int ki) {
        const bf16* Asrc;
        int kb;
        if (ki < 4) { Asrc = agg1b; kb = ki * 32; }
        else        { Asrc = xb;    kb = ki * 32 - IN_DIM; }
        int kw = ki * 32;
        int buf = ki & 1;
#pragma unroll
        for (int j = 0; j < 2; ++j) {
            int r = w * 32 + j * 16 + lr;
            GLDS(Asrc + (size_t)(row0 + r) * IN_DIM + kb + lc,
                 &As[buf][w * 32 + j * 16][0]);
            GLDS(Wt + (size_t)(n0 + r) * 256 + kw + lc,
                 &Bs[buf][w * 32 + j * 16][0]);
        }
    };

    f32x4 acc[4][4] = {};
    stage(0);
#pragma unroll
    for (int ki = 0; ki < 8; ++ki) {
        __syncthreads();                 // drains stage(ki); guards buf reuse
        if (ki + 1 < 8) stage(ki + 1);   // prefetch overlaps compute below
        int buf = ki & 1;
        bf16x8 af[4], bfr[4];
#pragma unroll
        for (int i = 0; i < 4; ++i)
            af[i] = *(const bf16x8*)&As[buf][wm + i * 16 + rr][q * 8];
#pragma unroll
        for (int j = 0; j < 4; ++j)
            bfr[j] = *(const bf16x8*)&Bs[buf][wn + j * 16 + rr][q * 8];
#pragma unroll
        for (int i = 0; i < 4; ++i)
#pragma unroll
            for (int j = 0; j < 4; ++j)
                acc[i][j] = __builtin_amdgcn_mfma_f32_16x16x32_bf16(
                    af[i], bfr[j], acc[i][j], 0, 0, 0);
    }
    __syncthreads();   // all compute done before Hs aliases As/Bs
    // ---- stage h tile (relu'd, bf16) into LDS
    float bias[4];
#pragma unroll
    for (int j = 0; j < 4; ++j) bias[j] = b1[n0 + wn + j * 16 + rr];
#pragma unroll
    for (int i = 0; i < 4; ++i) {
#pragma unroll
        for (int rg = 0; rg < 4; ++rg) {
            int mrow = wm + i * 16 + q * 4 + rg;
#pragma unroll
            for (int j = 0; j < 4; ++j)
                Hs[mrow][wn + j * 16 + rr] =
                    (bf16)fmaxf(acc[i][j][rg] + bias[j], 0.f);
        }
    }
    __syncthreads();
    // ---- z projection: [128 rows x K=128] @ W2bt^T (16 cols, 4 used)
    bf16x8 wf[4];
#pragma unroll
    for (int ks = 0; ks < 4; ++ks)
        wf[ks] = *(const bf16x8*)(W2bt + (size_t)rr * 512 + n0 + ks * 32 + q * 8);
    f32x4 zacc[2] = {};
#pragma unroll
    for (int mt = 0; mt < 2; ++mt)
#pragma unroll
        for (int ks = 0; ks < 4; ++ks) {
            bf16x8 afz = *(const bf16x8*)&Hs[w * 32 + mt * 16 + rr][ks * 32 + q * 8];
            zacc[mt] = __builtin_amdgcn_mfma_f32_16x16x32_bf16(
                afz, wf[ks], zacc[mt], 0, 0, 0);
        }
    if (rr < 4) {
#pragma unroll
        for (int mt = 0; mt < 2; ++mt)
#pragma unroll
            for (int rg = 0; rg < 4; ++rg) {
                int grow = row0 + w * 32 + mt * 16 + q * 4 + rg;
                zpart[(size_t)grow * 16 + cb * 4 + rr] = zacc[mt][rg];
            }
    }
}

// ---------------------------------------------------------------------------
// zsum: z[n][0..3] = sum of the 4 col-block partials.
// ---------------------------------------------------------------------------

__global__ __launch_bounds__(256) void zsum_kernel(const float* __restrict__ zpart,
                                                   float* __restrict__ z) {
    int n = blockIdx.x * blockDim.x + threadIdx.x;
    if (n >= N_NODES) return;
    const float4* p = (const float4*)(zpart + (size_t)n * 16);
    float4 a = p[0], b = p[1], c = p[2], d = p[3];
    float4 o = {a.x + b.x + c.x + d.x, a.y + b.y + c.y + d.y,
                a.z + b.z + c.z + d.z, a.w + b.w + c.w + d.w};
    *(float4*)(z + (size_t)n * 4) = o;
}

// ---------------------------------------------------------------------------
// final: out[n] = log_softmax(mean_e z[src][0..1] + b2 + z[n][2..3])
// ---------------------------------------------------------------------------

__global__ void final_kernel(const float* __restrict__ z, const int* __restrict__ offsets,
                             const int* __restrict__ csr_src, const float* __restrict__ b2,
                             float* __restrict__ out) {
    int n = blockIdx.x * blockDim.x + threadIdx.x;
    if (n >= N_NODES) return;
    int s0 = offsets[n], s1 = offsets[n + 1];
    float a0 = 0.f, a1 = 0.f;
    int e = s0;
    for (; e + 4 <= s1; e += 4) {
        int i0 = csr_src[e], i1 = csr_src[e + 1];
        int i2 = csr_src[e + 2], i3 = csr_src[e + 3];
        float2 v0 = *(const float2*)(z + (size_t)i0 * 4);
        float2 v1 = *(const float2*)(z + (size_t)i1 * 4);
        float2 v2 = *(const float2*)(z + (size_t)i2 * 4);
        float2 v3 = *(const float2*)(z + (size_t)i3 * 4);
        a0 += v0.x + v1.x + v2.x + v3.x;
        a1 += v0.y + v1.y + v2.y + v3.y;
    }
    for (; e < s1; ++e) {
        int s = csr_src[e];
        float2 v = *(const float2*)(z + (size_t)s * 4);
        a0 += v.x;
        a1 += v.y;
    }
    float inv = 1.0f / fmaxf((float)(s1 - s0), 1.0f);
    float2 zs = *(const float2*)(z + (size_t)n * 4 + 2);
    float o0 = a0 * inv + b2[0] + zs.x;
    float o1 = a1 * inv + b2[1] + zs.y;
    float m = fmaxf(o0, o1);
    float lse = logf(expf(o0 - m) + expf(o1 - m));
    float2 o = {o0 - m - lse, o1 - m - lse};
    *(float2*)(out + (size_t)n * 2) = o;
}

// ---------------------------------------------------------------------------

extern "C" void kernel_launch(void* const* d_in, const int* in_sizes, int n_in,
                              void* d_out, int out_size, void* d_ws, size_t ws_size,
                              hipStream_t stream) {
    const float* x   = (const float*)d_in[0];
    const float* W1l = (const float*)d_in[1];
    const float* b1  = (const float*)d_in[2];
    const float* W1r = (const float*)d_in[3];
    const float* W2l = (const float*)d_in[4];
    const float* b2  = (const float*)d_in[5];
    const float* W2r = (const float*)d_in[6];
    const int* edge  = (const int*)d_in[7];
    const int* src = edge;
    const int* dst = edge + N_EDGES;
    float* out = (float*)d_out;

    char* ws = (char*)d_ws;
    size_t off = 0;
    auto alloc = [&](size_t bytes) -> void* {
        void* p = ws + off;
        off += (bytes + 255) & ~(size_t)255;
        return p;
    };
    int* deg     = (int*)alloc((size_t)N_NODES * 4);
    int* offsets = (int*)alloc((size_t)(N_NODES + 1) * 4);
    int* cursor  = (int*)alloc((size_t)N_NODES * 4);
    int* csr_src = (int*)alloc((size_t)N_EDGES * 4);
    int* bsum    = (int*)alloc((size_t)SCAN_NB * 4);
    bf16* xb     = (bf16*)alloc((size_t)M_PAD * IN_DIM * 2);
    bf16* agg1b  = (bf16*)alloc((size_t)M_PAD * IN_DIM * 2);
    bf16* Wt     = (bf16*)alloc((size_t)HID_DIM * 256 * 2);
    bf16* W2bt   = (bf16*)alloc((size_t)16 * HID_DIM * 2);
    float* zpart = (float*)alloc((size_t)M_PAD * 16 * 4);
    float* z     = (float*)alloc((size_t)N_NODES * 4 * 4);

    hipMemsetAsync(deg, 0, (size_t)N_NODES * 4, stream);
    prep_kernel<<<CASTX_NB + DEG_NB + CASTW_NB, 256, 0, stream>>>(
        x, xb, dst, deg, W1l, W1r, W2l, W2r, Wt, W2bt);
    scan1_kernel<<<SCAN_NB, 256, 0, stream>>>(deg, bsum);
    scan3_kernel<<<SCAN_NB, 256, 0, stream>>>(deg, bsum, offsets, cursor);
    csr_fill_kernel<<<(N_EDGES + 255) / 256, 256, 0, stream>>>(src, dst, cursor, csr_src);
    agg1_kernel<<<N_NODES / 16, 256, 0, stream>>>(xb, offsets, csr_src, agg1b);
    gemm1_kernel<<<dim3(4, M_PAD / 128), 256, 0, stream>>>(
        agg1b, xb, Wt, b1, W2bt, zpart);
    zsum_kernel<<<(N_NODES + 255) / 256, 256, 0, stream>>>(zpart, z);
    final_kernel<<<(N_NODES + 255) / 256, 256, 0, stream>>>(z, offsets, csr_src, b2, out);
}